// Round 5
// baseline (2167.249 us; speedup 1.0000x reference)
//
#include <hip/hip_runtime.h>
#include <math.h>

// Problem geometry (B=8, N=4097, D=61, NPOINT=1024, NSAMPLE=16)
#define NB 8
#define NALL 4097
#define NPTS 4096            // N-1 points used for FPS/KNN
#define ND 61
#define NPOINT 1024
#define NS 16
#define XYZ_B_STRIDE 12291   // 4097*3
#define PTS_B_STRIDE 249917  // 4097*61
#define OUTXYZ_B 3075        // 1025*3
#define OUTPTS_B 131200      // 1025*128
#define OUT_PTS_OFF 24600    // 8*1025*3  (out_xyz block precedes out_pts)

// ---------------------------------------------------------------------------
// cls branch: 1 point per batch through 2-layer MLP. Also writes out_xyz[b,0].
// ---------------------------------------------------------------------------
__global__ __launch_bounds__(128)
void cls_kernel(const float* __restrict__ xyz, const float* __restrict__ pts,
                const float* __restrict__ w0, const float* __restrict__ b0,
                const float* __restrict__ g0, const float* __restrict__ bt0,
                const float* __restrict__ m0, const float* __restrict__ v0,
                const float* __restrict__ w1, const float* __restrict__ b1,
                const float* __restrict__ g1, const float* __restrict__ bt1,
                const float* __restrict__ m1, const float* __restrict__ v1,
                float* __restrict__ out)
{
    int b = blockIdx.x, t = threadIdx.x;
    __shared__ float in64[64];
    __shared__ float h[128];
    if (t < 64)
        in64[t] = (t < 3) ? xyz[b * XYZ_B_STRIDE + t]
                          : pts[(size_t)b * PTS_B_STRIDE + (t - 3)];
    __syncthreads();
    float A = g0[t] / sqrtf(v0[t] + 1e-5f);
    float B = (b0[t] - m0[t]) * A + bt0[t];
    float acc = 0.f;
    for (int c = 0; c < 64; ++c) acc = fmaf(w0[t * 64 + c], in64[c], acc);
    h[t] = fmaxf(acc * A + B, 0.f);
    __syncthreads();
    A = g1[t] / sqrtf(v1[t] + 1e-5f);
    B = (b1[t] - m1[t]) * A + bt1[t];
    acc = 0.f;
    for (int c = 0; c < 128; ++c) acc = fmaf(w1[t * 128 + c], h[c], acc);
    out[OUT_PTS_OFF + (size_t)b * OUTPTS_B + t] = fmaxf(acc * A + B, 0.f);
    if (t < 3) out[b * OUTXYZ_B + t] = xyz[b * XYZ_B_STRIDE + t];
}

// ---------------------------------------------------------------------------
// FPS: one block (256 thr = 4 waves) per batch. 1023 serial argmax steps.
// R3 change: reduce slots carry (wmax, cx, cy, cz) -- each wave fetches its
// OWN candidate's coords pre-barrier (wave-uniform LDS broadcast read), so
// the post-barrier path has no dependent center lookup. Index is never
// needed: ties resolve to the smallest wave id == smallest global index.
// All float math round-to-nearest, NO fma contraction (numpy bit-exactness
// of the discrete argmax decisions).
// ---------------------------------------------------------------------------
#define DPP_MAXSTEP(x, ctrl)                                                   \
    x = fmaxf(x, __int_as_float(__builtin_amdgcn_update_dpp(                   \
            0, __float_as_int(x), ctrl, 0xf, 0xf, true)))

__global__ __launch_bounds__(256)
void fps_kernel(const float* __restrict__ xyz, float4* __restrict__ nxyz,
                float* __restrict__ out)
{
#pragma clang fp contract(off)
    int b = blockIdx.x, tid = threadIdx.x;
    __shared__ float2 sxy[NPTS];              // 32 KB
    __shared__ float  szz[NPTS];              // 16 KB
    __shared__ float  cbx[NPOINT], cby[NPOINT], cbz[NPOINT];  // 12 KB
    __shared__ alignas(16) float4 pslot[2][4];

    float2 px[8], py[8], pz[8], dist[8];
    #pragma unroll
    for (int t = 0; t < 8; ++t) {
        int j = tid * 16 + t * 2;
        const float* p = xyz + b * XYZ_B_STRIDE + 3 + j * 3;  // xyz_r = xyz[:,1:]
        float x0 = p[0], y0 = p[1], z0 = p[2];
        float x1 = p[3], y1 = p[4], z1 = p[5];
        px[t] = make_float2(x0, x1);
        py[t] = make_float2(y0, y1);
        pz[t] = make_float2(z0, z1);
        dist[t] = make_float2(1e10f, 1e10f);
        sxy[j]     = make_float2(x0, y0);
        sxy[j + 1] = make_float2(x1, y1);
        szz[j] = z0; szz[j + 1] = z1;
    }
    __syncthreads();
    float2 c0 = sxy[0];
    float cx = c0.x, cy = c0.y, cz = szz[0];  // far_0 = 0
    if (tid == 0) { cbx[0] = cx; cby[0] = cy; cbz[0] = cz; }

    for (int s = 0; s < NPOINT - 1; ++s) {
        float nd[16];
        #pragma unroll
        for (int t = 0; t < 8; ++t) {
            float dx0 = px[t].x - cx, dx1 = px[t].y - cx;
            float dy0 = py[t].x - cy, dy1 = py[t].y - cy;
            float dz0 = pz[t].x - cz, dz1 = pz[t].y - cz;
            float d0 = (dx0 * dx0 + dy0 * dy0) + dz0 * dz0;
            float d1 = (dx1 * dx1 + dy1 * dy1) + dz1 * dz1;
            float n0 = fminf(dist[t].x, d0);
            float n1 = fminf(dist[t].y, d1);
            dist[t] = make_float2(n0, n1);
            nd[t * 2] = n0; nd[t * 2 + 1] = n1;
        }
        // per-lane max via v_max3-fusable tree (value only; ties resolved below)
        float g0 = fmaxf(fmaxf(nd[0], nd[1]), nd[2]);
        float g1 = fmaxf(fmaxf(nd[3], nd[4]), nd[5]);
        float g2 = fmaxf(fmaxf(nd[6], nd[7]), nd[8]);
        float g3 = fmaxf(fmaxf(nd[9], nd[10]), nd[11]);
        float g4 = fmaxf(fmaxf(nd[12], nd[13]), nd[14]);
        float h0 = fmaxf(fmaxf(g0, g1), g2);
        float h1 = fmaxf(fmaxf(g3, g4), nd[15]);
        float lmax = fmaxf(h0, h1);
        // smallest t achieving lmax (numpy first-max semantics)
        unsigned msk = 0;
        #pragma unroll
        for (int t = 0; t < 16; ++t) msk |= (nd[t] == lmax) ? (1u << t) : 0u;
        int mymi = (tid << 4) + (__ffs(msk) - 1);
        // wave max via DPP chain -> lane 63, then SGPR broadcast
        float red = lmax;
        DPP_MAXSTEP(red, 0x111);   // row_shr:1
        DPP_MAXSTEP(red, 0x112);   // row_shr:2
        DPP_MAXSTEP(red, 0x114);   // row_shr:4
        DPP_MAXSTEP(red, 0x118);   // row_shr:8
        DPP_MAXSTEP(red, 0x142);   // row_bcast:15
        DPP_MAXSTEP(red, 0x143);   // row_bcast:31  -> lane 63 has wave max
        float wmax = __int_as_float(__builtin_amdgcn_readlane(__float_as_int(red), 63));
        // lanes are index-ordered: lowest lane with lmax==wmax holds the
        // smallest qualifying global index
        unsigned long long ball = __ballot(lmax == wmax);
        int first = __ffsll((long long)ball) - 1;
        int bwi = __builtin_amdgcn_readlane(mymi, first);   // wave-uniform (SGPR)
        // fetch this wave's candidate coords (uniform-address broadcast reads)
        float2 cnd = sxy[bwi];
        float  cndz = szz[bwi];
        int par = s & 1;
        if ((tid & 63) == 0)
            pslot[par][tid >> 6] = make_float4(wmax, cnd.x, cnd.y, cndz);
        __syncthreads();
        float4 qa = pslot[par][0], qb = pslot[par][1];
        float4 qc = pslot[par][2], qd = pslot[par][3];
        float bv = qa.x; cx = qa.y; cy = qa.z; cz = qa.w;
        if (qb.x > bv) { bv = qb.x; cx = qb.y; cy = qb.z; cz = qb.w; }
        if (qc.x > bv) { bv = qc.x; cx = qc.y; cy = qc.z; cz = qc.w; }
        if (qd.x > bv) { bv = qd.x; cx = qd.y; cy = qd.z; cz = qd.w; }
        if (tid == 0) { cbx[s + 1] = cx; cby[s + 1] = cy; cbz[s + 1] = cz; }
    }
    __syncthreads();
    // single writeout of all centers (+|q|^2 for KNN)
    for (int s = tid; s < NPOINT; s += 256) {
        float x = cbx[s], y = cby[s], z = cbz[s];
        float s2 = (x * x + y * y) + z * z;   // rn, same assoc as reference
        float* o = out + b * OUTXYZ_B + 3 + s * 3;
        o[0] = x; o[1] = y; o[2] = z;
        nxyz[b * NPOINT + s] = make_float4(x, y, z, s2);
    }
}

// ---------------------------------------------------------------------------
// Fused KNN + gather + MLP(64->128->128) + maxpool. One block = 4 query rows.
// Phase 1 (KNN): wave per row, exact top-16 by (d2, idx); results in LDS.
// Phase 2 (MLP): 256 threads = 2 halves x 128 channels; half h handles
// neighbors k in [8h, 8h+8). xyz staging LDS is reused for the bit-exact
// g_xyz gather. Weights loaded AFTER the KNN phase (live-range separation).
// ---------------------------------------------------------------------------
__global__ __launch_bounds__(256, 2)
void group_kernel(const float* __restrict__ xyz, const float* __restrict__ pts,
                  const float4* __restrict__ nxyz,
                  const float* __restrict__ w0, const float* __restrict__ b0,
                  const float* __restrict__ g0, const float* __restrict__ bt0,
                  const float* __restrict__ m0, const float* __restrict__ v0,
                  const float* __restrict__ w1, const float* __restrict__ b1,
                  const float* __restrict__ g1, const float* __restrict__ bt1,
                  const float* __restrict__ m1, const float* __restrict__ v1,
                  float* __restrict__ out)
{
    int bb = blockIdx.x, tid = threadIdx.x;
    int b = bb >> 8;                 // 256 blocks per batch
    int sbase = (bb & 255) * 4;
    __shared__ float sx[NPTS], sy[NPTS], sz[NPTS], sn[NPTS];   // 64 KB
    __shared__ float feat[16 * 64];                             // 4 KB
    __shared__ float hbuf[16 * 128];                            // 8 KB
    __shared__ int   kk_sh[4][16];
    __shared__ float pm_sh[2][128];                             // 1 KB

    // ---- stage xyz (+ norms) ----
    #pragma unroll 1
    for (int t = 0; t < 16; ++t) {
        int j = tid + t * 256;
        const float* p = xyz + b * XYZ_B_STRIDE + 3 + j * 3;
        float x = p[0], y = p[1], z = p[2];
        sx[j] = x; sy[j] = y; sz[j] = z;
        sn[j] = __fadd_rn(__fadd_rn(__fmul_rn(x, x), __fmul_rn(y, y)), __fmul_rn(z, z));
    }
    __syncthreads();

    // ---- phase 1: KNN (wave per row) ----
    {
        int wid = tid >> 6, lane = tid & 63;
        int r = b * NPOINT + sbase + wid;
        float4 q = nxyz[r];

        float sv[16]; int si[16];
        #pragma unroll
        for (int k = 0; k < 16; ++k) { sv[k] = 3.0e38f; si[k] = 0x7fffffff; }

        #pragma unroll 1
        for (int t = 0; t < 64; ++t) {
            int j = (t << 6) + lane;
            float dot = __fadd_rn(__fadd_rn(__fmul_rn(q.x, sx[j]), __fmul_rn(q.y, sy[j])),
                                  __fmul_rn(q.z, sz[j]));
            float d2 = __fsub_rn(__fadd_rn(q.w, sn[j]), __fmul_rn(2.0f, dot));
            if (d2 < sv[15]) {            // strict <: equal value keeps earlier index
                sv[15] = d2; si[15] = j;
                #pragma unroll
                for (int k = 15; k > 0; --k) {
                    if (sv[k] < sv[k - 1]) {
                        float tv = sv[k]; sv[k] = sv[k - 1]; sv[k - 1] = tv;
                        int   ti = si[k]; si[k] = si[k - 1]; si[k - 1] = ti;
                    }
                }
            }
        }
        // merge 64 sorted lists: 16 rounds of wave argmin over the heads
        int mykn = 0;
        #pragma unroll 1
        for (int it = 0; it < 16; ++it) {
            float bvv = sv[0]; int bii = si[0];
            #pragma unroll
            for (int off = 32; off; off >>= 1) {
                float ov = __shfl_xor(bvv, off);
                int   oi = __shfl_xor(bii, off);
                if (ov < bvv || (ov == bvv && oi < bii)) { bvv = ov; bii = oi; }
            }
            if (lane == it) mykn = bii;
            bool win = (sv[0] == bvv) && (si[0] == bii);   // idx unique -> one winner
            if (win) {
                #pragma unroll
                for (int k = 0; k < 15; ++k) { sv[k] = sv[k + 1]; si[k] = si[k + 1]; }
                sv[15] = 3.0e38f; si[15] = 0x7fffffff;
            }
        }
        if (lane < 16) kk_sh[wid][lane] = mykn;
    }
    __syncthreads();

    // ---- phase 2: MLP. h = k-half, ch = output channel ----
    int h = tid >> 7, ch = tid & 127;
    float4 w0r[16], w1r[32];
    const float4* w0p = (const float4*)(w0 + ch * 64);
    #pragma unroll
    for (int i = 0; i < 16; ++i) w0r[i] = w0p[i];
    const float4* w1p = (const float4*)(w1 + ch * 128);
    #pragma unroll
    for (int i = 0; i < 32; ++i) w1r[i] = w1p[i];
    float A0 = g0[ch] / sqrtf(v0[ch] + 1e-5f);
    float B0 = (b0[ch] - m0[ch]) * A0 + bt0[ch];
    float A1 = g1[ch] / sqrtf(v1[ch] + 1e-5f);
    float B1 = (b1[ch] - m1[ch]) * A1 + bt1[ch];

    for (int row = 0; row < 4; ++row) {
        int s = sbase + row;
        float4 nq = nxyz[b * NPOINT + s];
        // gather: 4 feat elements per thread; g_xyz from staged LDS (bit-exact)
        #pragma unroll
        for (int i = 0; i < 4; ++i) {
            int e = tid + (i << 8);
            int k = e >> 6, c = e & 63;
            int j = kk_sh[row][k];
            float v;
            if (c < 3) {
                float g = (c == 0) ? sx[j] : ((c == 1) ? sy[j] : sz[j]);
                float n = (c == 0) ? nq.x : ((c == 1) ? nq.y : nq.z);
                v = __fsub_rn(g, n);
            } else {
                v = pts[(size_t)b * PTS_B_STRIDE + 61 + (size_t)j * 61 + (c - 3)];
            }
            feat[e] = v;
        }
        __syncthreads();
        // layer0: my 8 k's (broadcast LDS reads)
        #pragma unroll 1
        for (int kx = 0; kx < 8; ++kx) {
            int k = h * 8 + kx;
            const float4* fv = (const float4*)(feat + (k << 6));
            float acc = 0.f;
            #pragma unroll
            for (int i = 0; i < 16; ++i) {
                float4 f = fv[i];
                acc = fmaf(w0r[i].x, f.x, acc);
                acc = fmaf(w0r[i].y, f.y, acc);
                acc = fmaf(w0r[i].z, f.z, acc);
                acc = fmaf(w0r[i].w, f.w, acc);
            }
            hbuf[(k << 7) + ch] = fmaxf(acc * A0 + B0, 0.f);
        }
        __syncthreads();
        // layer1 + partial max over my 8 k's
        float mx = 0.f;                 // relu outputs >= 0
        #pragma unroll 1
        for (int kx = 0; kx < 8; ++kx) {
            int k = h * 8 + kx;
            const float4* hv = (const float4*)(hbuf + (k << 7));
            float acc = 0.f;
            #pragma unroll
            for (int i = 0; i < 32; ++i) {
                float4 f = hv[i];
                acc = fmaf(w1r[i].x, f.x, acc);
                acc = fmaf(w1r[i].y, f.y, acc);
                acc = fmaf(w1r[i].z, f.z, acc);
                acc = fmaf(w1r[i].w, f.w, acc);
            }
            mx = fmaxf(mx, fmaxf(acc * A1 + B1, 0.f));
        }
        pm_sh[h][ch] = mx;
        __syncthreads();
        if (tid < 128)
            out[OUT_PTS_OFF + (size_t)b * OUTPTS_B + (size_t)(1 + s) * 128 + tid]
                = fmaxf(pm_sh[0][tid], pm_sh[1][tid]);
        // feat/hbuf rewritten only after the next row's barriers; kk_sh read-only
    }
}

// ---------------------------------------------------------------------------
extern "C" void kernel_launch(void* const* d_in, const int* in_sizes, int n_in,
                              void* d_out, int out_size, void* d_ws, size_t ws_size,
                              hipStream_t stream) {
    const float* xyz = (const float*)d_in[0];
    const float* pts = (const float*)d_in[1];
    // dict order: sa0 block, cls0 block, sa1 block, cls1 block
    const float* sa_w0 = (const float*)d_in[2];
    const float* sa_b0 = (const float*)d_in[3];
    const float* sa_g0 = (const float*)d_in[4];
    const float* sa_bt0 = (const float*)d_in[5];
    const float* sa_m0 = (const float*)d_in[6];
    const float* sa_v0 = (const float*)d_in[7];
    const float* cls_w0 = (const float*)d_in[8];
    const float* cls_b0 = (const float*)d_in[9];
    const float* cls_g0 = (const float*)d_in[10];
    const float* cls_bt0 = (const float*)d_in[11];
    const float* cls_m0 = (const float*)d_in[12];
    const float* cls_v0 = (const float*)d_in[13];
    const float* sa_w1 = (const float*)d_in[14];
    const float* sa_b1 = (const float*)d_in[15];
    const float* sa_g1 = (const float*)d_in[16];
    const float* sa_bt1 = (const float*)d_in[17];
    const float* sa_m1 = (const float*)d_in[18];
    const float* sa_v1 = (const float*)d_in[19];
    const float* cls_w1 = (const float*)d_in[20];
    const float* cls_b1 = (const float*)d_in[21];
    const float* cls_g1 = (const float*)d_in[22];
    const float* cls_bt1 = (const float*)d_in[23];
    const float* cls_m1 = (const float*)d_in[24];
    const float* cls_v1 = (const float*)d_in[25];

    float* out = (float*)d_out;
    float4* nxyz_ws = (float4*)d_ws;                          // 8192 * 16 B

    cls_kernel<<<NB, 128, 0, stream>>>(xyz, pts,
        cls_w0, cls_b0, cls_g0, cls_bt0, cls_m0, cls_v0,
        cls_w1, cls_b1, cls_g1, cls_bt1, cls_m1, cls_v1, out);
    fps_kernel<<<NB, 256, 0, stream>>>(xyz, nxyz_ws, out);
    group_kernel<<<NB * (NPOINT / 4), 256, 0, stream>>>(xyz, pts, nxyz_ws,
        sa_w0, sa_b0, sa_g0, sa_bt0, sa_m0, sa_v0,
        sa_w1, sa_b1, sa_g1, sa_bt1, sa_m1, sa_v1, out);
}

// Round 6
// 1253.978 us; speedup vs baseline: 1.7283x; 1.7283x over previous
//
#include <hip/hip_runtime.h>
#include <math.h>

// Problem geometry (B=8, N=4097, D=61, NPOINT=1024, NSAMPLE=16)
#define NB 8
#define NALL 4097
#define NPTS 4096            // N-1 points used for FPS/KNN
#define ND 61
#define NPOINT 1024
#define NS 16
#define XYZ_B_STRIDE 12291   // 4097*3
#define PTS_B_STRIDE 249917  // 4097*61
#define OUTXYZ_B 3075        // 1025*3
#define OUTPTS_B 131200      // 1025*128
#define OUT_PTS_OFF 24600    // 8*1025*3  (out_xyz block precedes out_pts)

// ---------------------------------------------------------------------------
// cls branch: 1 point per batch through 2-layer MLP. Also writes out_xyz[b,0].
// ---------------------------------------------------------------------------
__global__ __launch_bounds__(128)
void cls_kernel(const float* __restrict__ xyz, const float* __restrict__ pts,
                const float* __restrict__ w0, const float* __restrict__ b0,
                const float* __restrict__ g0, const float* __restrict__ bt0,
                const float* __restrict__ m0, const float* __restrict__ v0,
                const float* __restrict__ w1, const float* __restrict__ b1,
                const float* __restrict__ g1, const float* __restrict__ bt1,
                const float* __restrict__ m1, const float* __restrict__ v1,
                float* __restrict__ out)
{
    int b = blockIdx.x, t = threadIdx.x;
    __shared__ float in64[64];
    __shared__ float h[128];
    if (t < 64)
        in64[t] = (t < 3) ? xyz[b * XYZ_B_STRIDE + t]
                          : pts[(size_t)b * PTS_B_STRIDE + (t - 3)];
    __syncthreads();
    float A = g0[t] / sqrtf(v0[t] + 1e-5f);
    float B = (b0[t] - m0[t]) * A + bt0[t];
    float acc = 0.f;
    for (int c = 0; c < 64; ++c) acc = fmaf(w0[t * 64 + c], in64[c], acc);
    h[t] = fmaxf(acc * A + B, 0.f);
    __syncthreads();
    A = g1[t] / sqrtf(v1[t] + 1e-5f);
    B = (b1[t] - m1[t]) * A + bt1[t];
    acc = 0.f;
    for (int c = 0; c < 128; ++c) acc = fmaf(w1[t * 128 + c], h[c], acc);
    out[OUT_PTS_OFF + (size_t)b * OUTPTS_B + t] = fmaxf(acc * A + B, 0.f);
    if (t < 3) out[b * OUTXYZ_B + t] = xyz[b * XYZ_B_STRIDE + t];
}

// ---------------------------------------------------------------------------
// FPS: one block (256 thr = 4 waves) per batch. 1023 serial argmax steps.
// Reduce slots carry (wmax, cx, cy, cz) -- each wave fetches its OWN
// candidate's coords pre-barrier (wave-uniform LDS broadcast read), so the
// post-barrier path has no dependent center lookup. Ties resolve to the
// smallest wave id == smallest global index.
// All float math round-to-nearest, NO fma contraction (numpy bit-exactness
// of the discrete argmax decisions).
// ---------------------------------------------------------------------------
#define DPP_MAXSTEP(x, ctrl)                                                   \
    x = fmaxf(x, __int_as_float(__builtin_amdgcn_update_dpp(                   \
            0, __float_as_int(x), ctrl, 0xf, 0xf, true)))

__global__ __launch_bounds__(256)
void fps_kernel(const float* __restrict__ xyz, float4* __restrict__ nxyz,
                float* __restrict__ out)
{
#pragma clang fp contract(off)
    int b = blockIdx.x, tid = threadIdx.x;
    __shared__ float2 sxy[NPTS];              // 32 KB
    __shared__ float  szz[NPTS];              // 16 KB
    __shared__ float  cbx[NPOINT], cby[NPOINT], cbz[NPOINT];  // 12 KB
    __shared__ alignas(16) float4 pslot[2][4];

    float2 px[8], py[8], pz[8], dist[8];
    #pragma unroll
    for (int t = 0; t < 8; ++t) {
        int j = tid * 16 + t * 2;
        const float* p = xyz + b * XYZ_B_STRIDE + 3 + j * 3;  // xyz_r = xyz[:,1:]
        float x0 = p[0], y0 = p[1], z0 = p[2];
        float x1 = p[3], y1 = p[4], z1 = p[5];
        px[t] = make_float2(x0, x1);
        py[t] = make_float2(y0, y1);
        pz[t] = make_float2(z0, z1);
        dist[t] = make_float2(1e10f, 1e10f);
        sxy[j]     = make_float2(x0, y0);
        sxy[j + 1] = make_float2(x1, y1);
        szz[j] = z0; szz[j + 1] = z1;
    }
    __syncthreads();
    float2 c0 = sxy[0];
    float cx = c0.x, cy = c0.y, cz = szz[0];  // far_0 = 0
    if (tid == 0) { cbx[0] = cx; cby[0] = cy; cbz[0] = cz; }

    for (int s = 0; s < NPOINT - 1; ++s) {
        float nd[16];
        #pragma unroll
        for (int t = 0; t < 8; ++t) {
            float dx0 = px[t].x - cx, dx1 = px[t].y - cx;
            float dy0 = py[t].x - cy, dy1 = py[t].y - cy;
            float dz0 = pz[t].x - cz, dz1 = pz[t].y - cz;
            float d0 = (dx0 * dx0 + dy0 * dy0) + dz0 * dz0;
            float d1 = (dx1 * dx1 + dy1 * dy1) + dz1 * dz1;
            float n0 = fminf(dist[t].x, d0);
            float n1 = fminf(dist[t].y, d1);
            dist[t] = make_float2(n0, n1);
            nd[t * 2] = n0; nd[t * 2 + 1] = n1;
        }
        // per-lane max via v_max3-fusable tree (value only; ties resolved below)
        float g0 = fmaxf(fmaxf(nd[0], nd[1]), nd[2]);
        float g1 = fmaxf(fmaxf(nd[3], nd[4]), nd[5]);
        float g2 = fmaxf(fmaxf(nd[6], nd[7]), nd[8]);
        float g3 = fmaxf(fmaxf(nd[9], nd[10]), nd[11]);
        float g4 = fmaxf(fmaxf(nd[12], nd[13]), nd[14]);
        float h0 = fmaxf(fmaxf(g0, g1), g2);
        float h1 = fmaxf(fmaxf(g3, g4), nd[15]);
        float lmax = fmaxf(h0, h1);
        // smallest t achieving lmax (numpy first-max semantics)
        unsigned msk = 0;
        #pragma unroll
        for (int t = 0; t < 16; ++t) msk |= (nd[t] == lmax) ? (1u << t) : 0u;
        int mymi = (tid << 4) + (__ffs(msk) - 1);
        // wave max via DPP chain -> lane 63, then SGPR broadcast
        float red = lmax;
        DPP_MAXSTEP(red, 0x111);   // row_shr:1
        DPP_MAXSTEP(red, 0x112);   // row_shr:2
        DPP_MAXSTEP(red, 0x114);   // row_shr:4
        DPP_MAXSTEP(red, 0x118);   // row_shr:8
        DPP_MAXSTEP(red, 0x142);   // row_bcast:15
        DPP_MAXSTEP(red, 0x143);   // row_bcast:31  -> lane 63 has wave max
        float wmax = __int_as_float(__builtin_amdgcn_readlane(__float_as_int(red), 63));
        // lanes are index-ordered: lowest lane with lmax==wmax holds the
        // smallest qualifying global index
        unsigned long long ball = __ballot(lmax == wmax);
        int first = __ffsll((long long)ball) - 1;
        int bwi = __builtin_amdgcn_readlane(mymi, first);   // wave-uniform (SGPR)
        // fetch this wave's candidate coords (uniform-address broadcast reads)
        float2 cnd = sxy[bwi];
        float  cndz = szz[bwi];
        int par = s & 1;
        if ((tid & 63) == 0)
            pslot[par][tid >> 6] = make_float4(wmax, cnd.x, cnd.y, cndz);
        __syncthreads();
        float4 qa = pslot[par][0], qb = pslot[par][1];
        float4 qc = pslot[par][2], qd = pslot[par][3];
        float bv = qa.x; cx = qa.y; cy = qa.z; cz = qa.w;
        if (qb.x > bv) { bv = qb.x; cx = qb.y; cy = qb.z; cz = qb.w; }
        if (qc.x > bv) { bv = qc.x; cx = qc.y; cy = qc.z; cz = qc.w; }
        if (qd.x > bv) { bv = qd.x; cx = qd.y; cy = qd.z; cz = qd.w; }
        if (tid == 0) { cbx[s + 1] = cx; cby[s + 1] = cy; cbz[s + 1] = cz; }
    }
    __syncthreads();
    // single writeout of all centers (+|q|^2 for KNN)
    for (int s = tid; s < NPOINT; s += 256) {
        float x = cbx[s], y = cby[s], z = cbz[s];
        float s2 = (x * x + y * y) + z * z;   // rn, same assoc as reference
        float* o = out + b * OUTXYZ_B + 3 + s * 3;
        o[0] = x; o[1] = y; o[2] = z;
        nxyz[b * NPOINT + s] = make_float4(x, y, z, s2);
    }
}

// ---------------------------------------------------------------------------
// Fused KNN + gather + MLP(64->128->128) + maxpool. One block = 4 query rows.
// Phase 1 (KNN): wave per row, exact top-16 by (d2, idx); results in LDS.
// Phase 2 (MLP): PAIR-SPLIT channel mapping (R5 spill fix): 2 threads per
// output channel (h = tid&1 owns input half), so per-thread weights are
// 8+16 float4 = 96 VGPRs instead of 192 (which spilled to scratch under the
// 128-VGPR cap: 688 MB scratch writes/dispatch). Partial dots combined with
// one lane-adjacent __shfl_xor. No launch-bounds min-occupancy arg: LDS
// (77.5 KB) already caps at 2 blocks/CU; let RA use what it needs.
// ---------------------------------------------------------------------------
__global__ __launch_bounds__(256)
void group_kernel(const float* __restrict__ xyz, const float* __restrict__ pts,
                  const float4* __restrict__ nxyz,
                  const float* __restrict__ w0, const float* __restrict__ b0,
                  const float* __restrict__ g0, const float* __restrict__ bt0,
                  const float* __restrict__ m0, const float* __restrict__ v0,
                  const float* __restrict__ w1, const float* __restrict__ b1,
                  const float* __restrict__ g1, const float* __restrict__ bt1,
                  const float* __restrict__ m1, const float* __restrict__ v1,
                  float* __restrict__ out)
{
    int bb = blockIdx.x, tid = threadIdx.x;
    int b = bb >> 8;                 // 256 blocks per batch
    int sbase = (bb & 255) * 4;
    __shared__ float sx[NPTS], sy[NPTS], sz[NPTS], sn[NPTS];   // 64 KB
    __shared__ float feat[16 * 64];                             // 4 KB
    __shared__ float hbuf[16 * 128];                            // 8 KB
    __shared__ int   kk_sh[4][16];

    // ---- stage xyz (+ norms) ----
    #pragma unroll 1
    for (int t = 0; t < 16; ++t) {
        int j = tid + t * 256;
        const float* p = xyz + b * XYZ_B_STRIDE + 3 + j * 3;
        float x = p[0], y = p[1], z = p[2];
        sx[j] = x; sy[j] = y; sz[j] = z;
        sn[j] = __fadd_rn(__fadd_rn(__fmul_rn(x, x), __fmul_rn(y, y)), __fmul_rn(z, z));
    }
    __syncthreads();

    // ---- phase 1: KNN (wave per row) ----
    {
        int wid = tid >> 6, lane = tid & 63;
        int r = b * NPOINT + sbase + wid;
        float4 q = nxyz[r];

        float sv[16]; int si[16];
        #pragma unroll
        for (int k = 0; k < 16; ++k) { sv[k] = 3.0e38f; si[k] = 0x7fffffff; }

        #pragma unroll 1
        for (int t = 0; t < 64; ++t) {
            int j = (t << 6) + lane;
            float dot = __fadd_rn(__fadd_rn(__fmul_rn(q.x, sx[j]), __fmul_rn(q.y, sy[j])),
                                  __fmul_rn(q.z, sz[j]));
            float d2 = __fsub_rn(__fadd_rn(q.w, sn[j]), __fmul_rn(2.0f, dot));
            if (d2 < sv[15]) {            // strict <: equal value keeps earlier index
                sv[15] = d2; si[15] = j;
                #pragma unroll
                for (int k = 15; k > 0; --k) {
                    if (sv[k] < sv[k - 1]) {
                        float tv = sv[k]; sv[k] = sv[k - 1]; sv[k - 1] = tv;
                        int   ti = si[k]; si[k] = si[k - 1]; si[k - 1] = ti;
                    }
                }
            }
        }
        // merge 64 sorted lists: 16 rounds of wave argmin over the heads
        int mykn = 0;
        #pragma unroll 1
        for (int it = 0; it < 16; ++it) {
            float bvv = sv[0]; int bii = si[0];
            #pragma unroll
            for (int off = 32; off; off >>= 1) {
                float ov = __shfl_xor(bvv, off);
                int   oi = __shfl_xor(bii, off);
                if (ov < bvv || (ov == bvv && oi < bii)) { bvv = ov; bii = oi; }
            }
            if (lane == it) mykn = bii;
            bool win = (sv[0] == bvv) && (si[0] == bii);   // idx unique -> one winner
            if (win) {
                #pragma unroll
                for (int k = 0; k < 15; ++k) { sv[k] = sv[k + 1]; si[k] = si[k + 1]; }
                sv[15] = 3.0e38f; si[15] = 0x7fffffff;
            }
        }
        if (lane < 16) kk_sh[wid][lane] = mykn;
    }
    __syncthreads();

    // ---- phase 2: MLP, pair-split. h2 = input half, ch = output channel ----
    int h2 = tid & 1, ch = tid >> 1;
    float4 w0r[8], w1r[16];                      // 96 VGPRs total — no spill
    const float4* w0p = (const float4*)(w0 + ch * 64 + h2 * 32);
    #pragma unroll
    for (int i = 0; i < 8; ++i) w0r[i] = w0p[i];
    const float4* w1p = (const float4*)(w1 + ch * 128 + h2 * 64);
    #pragma unroll
    for (int i = 0; i < 16; ++i) w1r[i] = w1p[i];
    float A0 = g0[ch] / sqrtf(v0[ch] + 1e-5f);
    float B0 = (b0[ch] - m0[ch]) * A0 + bt0[ch];
    float A1 = g1[ch] / sqrtf(v1[ch] + 1e-5f);
    float B1 = (b1[ch] - m1[ch]) * A1 + bt1[ch];

    for (int row = 0; row < 4; ++row) {
        int s = sbase + row;
        float4 nq = nxyz[b * NPOINT + s];
        // gather: 4 feat elements per thread; g_xyz from staged LDS (bit-exact)
        #pragma unroll
        for (int i = 0; i < 4; ++i) {
            int e = tid + (i << 8);
            int k = e >> 6, c = e & 63;
            int j = kk_sh[row][k];
            float v;
            if (c < 3) {
                float g = (c == 0) ? sx[j] : ((c == 1) ? sy[j] : sz[j]);
                float n = (c == 0) ? nq.x : ((c == 1) ? nq.y : nq.z);
                v = __fsub_rn(g, n);
            } else {
                v = pts[(size_t)b * PTS_B_STRIDE + 61 + (size_t)j * 61 + (c - 3)];
            }
            feat[e] = v;
        }
        __syncthreads();
        // layer0: all 16 k's, my input half (broadcast LDS reads)
        #pragma unroll 1
        for (int k = 0; k < 16; ++k) {
            const float4* fv = (const float4*)(feat + (k << 6) + (h2 << 5));
            float acc = 0.f;
            #pragma unroll
            for (int i = 0; i < 8; ++i) {
                float4 f = fv[i];
                acc = fmaf(w0r[i].x, f.x, acc);
                acc = fmaf(w0r[i].y, f.y, acc);
                acc = fmaf(w0r[i].z, f.z, acc);
                acc = fmaf(w0r[i].w, f.w, acc);
            }
            acc += __shfl_xor(acc, 1);           // combine halves (lane pair)
            if (h2 == 0) hbuf[(k << 7) + ch] = fmaxf(acc * A0 + B0, 0.f);
        }
        __syncthreads();
        // layer1 + max over all 16 k's, my input half
        float mx = 0.f;                 // relu outputs >= 0
        #pragma unroll 1
        for (int k = 0; k < 16; ++k) {
            const float4* hv = (const float4*)(hbuf + (k << 7) + (h2 << 6));
            float acc = 0.f;
            #pragma unroll
            for (int i = 0; i < 16; ++i) {
                float4 f = hv[i];
                acc = fmaf(w1r[i].x, f.x, acc);
                acc = fmaf(w1r[i].y, f.y, acc);
                acc = fmaf(w1r[i].z, f.z, acc);
                acc = fmaf(w1r[i].w, f.w, acc);
            }
            acc += __shfl_xor(acc, 1);           // combine halves (lane pair)
            mx = fmaxf(mx, fmaxf(acc * A1 + B1, 0.f));
        }
        if (h2 == 0)
            out[OUT_PTS_OFF + (size_t)b * OUTPTS_B + (size_t)(1 + s) * 128 + ch] = mx;
        __syncthreads();   // protect feat/hbuf before next row overwrites
    }
}

// ---------------------------------------------------------------------------
extern "C" void kernel_launch(void* const* d_in, const int* in_sizes, int n_in,
                              void* d_out, int out_size, void* d_ws, size_t ws_size,
                              hipStream_t stream) {
    const float* xyz = (const float*)d_in[0];
    const float* pts = (const float*)d_in[1];
    // dict order: sa0 block, cls0 block, sa1 block, cls1 block
    const float* sa_w0 = (const float*)d_in[2];
    const float* sa_b0 = (const float*)d_in[3];
    const float* sa_g0 = (const float*)d_in[4];
    const float* sa_bt0 = (const float*)d_in[5];
    const float* sa_m0 = (const float*)d_in[6];
    const float* sa_v0 = (const float*)d_in[7];
    const float* cls_w0 = (const float*)d_in[8];
    const float* cls_b0 = (const float*)d_in[9];
    const float* cls_g0 = (const float*)d_in[10];
    const float* cls_bt0 = (const float*)d_in[11];
    const float* cls_m0 = (const float*)d_in[12];
    const float* cls_v0 = (const float*)d_in[13];
    const float* sa_w1 = (const float*)d_in[14];
    const float* sa_b1 = (const float*)d_in[15];
    const float* sa_g1 = (const float*)d_in[16];
    const float* sa_bt1 = (const float*)d_in[17];
    const float* sa_m1 = (const float*)d_in[18];
    const float* sa_v1 = (const float*)d_in[19];
    const float* cls_w1 = (const float*)d_in[20];
    const float* cls_b1 = (const float*)d_in[21];
    const float* cls_g1 = (const float*)d_in[22];
    const float* cls_bt1 = (const float*)d_in[23];
    const float* cls_m1 = (const float*)d_in[24];
    const float* cls_v1 = (const float*)d_in[25];

    float* out = (float*)d_out;
    float4* nxyz_ws = (float4*)d_ws;                          // 8192 * 16 B

    cls_kernel<<<NB, 128, 0, stream>>>(xyz, pts,
        cls_w0, cls_b0, cls_g0, cls_bt0, cls_m0, cls_v0,
        cls_w1, cls_b1, cls_g1, cls_bt1, cls_m1, cls_v1, out);
    fps_kernel<<<NB, 256, 0, stream>>>(xyz, nxyz_ws, out);
    group_kernel<<<NB * (NPOINT / 4), 256, 0, stream>>>(xyz, pts, nxyz_ws,
        sa_w0, sa_b0, sa_g0, sa_bt0, sa_m0, sa_v0,
        sa_w1, sa_b1, sa_g1, sa_bt1, sa_m1, sa_v1, out);
}

// Round 8
// 1096.479 us; speedup vs baseline: 1.9766x; 1.1436x over previous
//
#include <hip/hip_runtime.h>
#include <math.h>

// Problem geometry (B=8, N=4097, D=61, NPOINT=1024, NSAMPLE=16)
#define NB 8
#define NALL 4097
#define NPTS 4096            // N-1 points used for FPS/KNN
#define ND 61
#define NPOINT 1024
#define NS 16
#define XYZ_B_STRIDE 12291   // 4097*3
#define PTS_B_STRIDE 249917  // 4097*61
#define OUTXYZ_B 3075        // 1025*3
#define OUTPTS_B 131200      // 1025*128
#define OUT_PTS_OFF 24600    // 8*1025*3  (out_xyz block precedes out_pts)

// ---------------------------------------------------------------------------
// cls branch: 1 point per batch through 2-layer MLP. Also writes out_xyz[b,0].
// ---------------------------------------------------------------------------
__global__ __launch_bounds__(128)
void cls_kernel(const float* __restrict__ xyz, const float* __restrict__ pts,
                const float* __restrict__ w0, const float* __restrict__ b0,
                const float* __restrict__ g0, const float* __restrict__ bt0,
                const float* __restrict__ m0, const float* __restrict__ v0,
                const float* __restrict__ w1, const float* __restrict__ b1,
                const float* __restrict__ g1, const float* __restrict__ bt1,
                const float* __restrict__ m1, const float* __restrict__ v1,
                float* __restrict__ out)
{
    int b = blockIdx.x, t = threadIdx.x;
    __shared__ float in64[64];
    __shared__ float h[128];
    if (t < 64)
        in64[t] = (t < 3) ? xyz[b * XYZ_B_STRIDE + t]
                          : pts[(size_t)b * PTS_B_STRIDE + (t - 3)];
    __syncthreads();
    float A = g0[t] / sqrtf(v0[t] + 1e-5f);
    float B = (b0[t] - m0[t]) * A + bt0[t];
    float acc = 0.f;
    for (int c = 0; c < 64; ++c) acc = fmaf(w0[t * 64 + c], in64[c], acc);
    h[t] = fmaxf(acc * A + B, 0.f);
    __syncthreads();
    A = g1[t] / sqrtf(v1[t] + 1e-5f);
    B = (b1[t] - m1[t]) * A + bt1[t];
    acc = 0.f;
    for (int c = 0; c < 128; ++c) acc = fmaf(w1[t * 128 + c], h[c], acc);
    out[OUT_PTS_OFF + (size_t)b * OUTPTS_B + t] = fmaxf(acc * A + B, 0.f);
    if (t < 3) out[b * OUTXYZ_B + t] = xyz[b * XYZ_B_STRIDE + t];
}

// ---------------------------------------------------------------------------
// FPS: one block (256 thr = 4 waves) per batch. 1023 serial argmax steps.
// EXACT R2 structure (index-carry): measured 622-635 us; the R3 coord-carry
// variant measured 740 us -> reverted. Slots carry (wmax, idx); combine is
// followed by a dependent sxy[bi]/szz[bi] broadcast fetch.
// All float math round-to-nearest, NO fma contraction (numpy bit-exactness
// of the discrete argmax decisions).
// ---------------------------------------------------------------------------
#define DPP_MAXSTEP(x, ctrl)                                                   \
    x = fmaxf(x, __int_as_float(__builtin_amdgcn_update_dpp(                   \
            0, __float_as_int(x), ctrl, 0xf, 0xf, true)))

__global__ __launch_bounds__(256)
void fps_kernel(const float* __restrict__ xyz, float4* __restrict__ nxyz,
                float* __restrict__ out)
{
#pragma clang fp contract(off)
    int b = blockIdx.x, tid = threadIdx.x;
    __shared__ float2 sxy[NPTS];              // 32 KB
    __shared__ float  szz[NPTS];              // 16 KB
    __shared__ float  cbx[NPOINT], cby[NPOINT], cbz[NPOINT];  // 12 KB
    __shared__ alignas(16) float2 pvpi[2][4];

    float2 px[8], py[8], pz[8], dist[8];
    #pragma unroll
    for (int t = 0; t < 8; ++t) {
        int j = tid * 16 + t * 2;
        const float* p = xyz + b * XYZ_B_STRIDE + 3 + j * 3;  // xyz_r = xyz[:,1:]
        float x0 = p[0], y0 = p[1], z0 = p[2];
        float x1 = p[3], y1 = p[4], z1 = p[5];
        px[t] = make_float2(x0, x1);
        py[t] = make_float2(y0, y1);
        pz[t] = make_float2(z0, z1);
        dist[t] = make_float2(1e10f, 1e10f);
        sxy[j]     = make_float2(x0, y0);
        sxy[j + 1] = make_float2(x1, y1);
        szz[j] = z0; szz[j + 1] = z1;
    }
    __syncthreads();
    float2 c0 = sxy[0];
    float cx = c0.x, cy = c0.y, cz = szz[0];  // far_0 = 0
    if (tid == 0) { cbx[0] = cx; cby[0] = cy; cbz[0] = cz; }

    for (int s = 0; s < NPOINT - 1; ++s) {
        float nd[16];
        #pragma unroll
        for (int t = 0; t < 8; ++t) {
            float dx0 = px[t].x - cx, dx1 = px[t].y - cx;
            float dy0 = py[t].x - cy, dy1 = py[t].y - cy;
            float dz0 = pz[t].x - cz, dz1 = pz[t].y - cz;
            float d0 = (dx0 * dx0 + dy0 * dy0) + dz0 * dz0;
            float d1 = (dx1 * dx1 + dy1 * dy1) + dz1 * dz1;
            float n0 = fminf(dist[t].x, d0);
            float n1 = fminf(dist[t].y, d1);
            dist[t] = make_float2(n0, n1);
            nd[t * 2] = n0; nd[t * 2 + 1] = n1;
        }
        // per-lane max via v_max3-fusable tree (value only; ties resolved below)
        float g0 = fmaxf(fmaxf(nd[0], nd[1]), nd[2]);
        float g1 = fmaxf(fmaxf(nd[3], nd[4]), nd[5]);
        float g2 = fmaxf(fmaxf(nd[6], nd[7]), nd[8]);
        float g3 = fmaxf(fmaxf(nd[9], nd[10]), nd[11]);
        float g4 = fmaxf(fmaxf(nd[12], nd[13]), nd[14]);
        float h0 = fmaxf(fmaxf(g0, g1), g2);
        float h1 = fmaxf(fmaxf(g3, g4), nd[15]);
        float lmax = fmaxf(h0, h1);
        // smallest t achieving lmax (numpy first-max semantics)
        unsigned msk = 0;
        #pragma unroll
        for (int t = 0; t < 16; ++t) msk |= (nd[t] == lmax) ? (1u << t) : 0u;
        int mymi = (tid << 4) + (__ffs(msk) - 1);
        // wave max via DPP chain -> lane 63, then SGPR broadcast
        float red = lmax;
        DPP_MAXSTEP(red, 0x111);   // row_shr:1
        DPP_MAXSTEP(red, 0x112);   // row_shr:2
        DPP_MAXSTEP(red, 0x114);   // row_shr:4
        DPP_MAXSTEP(red, 0x118);   // row_shr:8
        DPP_MAXSTEP(red, 0x142);   // row_bcast:15
        DPP_MAXSTEP(red, 0x143);   // row_bcast:31  -> lane 63 has wave max
        float wmax = __int_as_float(__builtin_amdgcn_readlane(__float_as_int(red), 63));
        // lanes are index-ordered: lowest lane with lmax==wmax holds the
        // smallest qualifying global index
        unsigned long long ball = __ballot(lmax == wmax);
        int first = __ffsll((long long)ball) - 1;
        int bwi = __builtin_amdgcn_readlane(mymi, first);
        int par = s & 1;
        if ((tid & 63) == 0)
            pvpi[par][tid >> 6] = make_float2(wmax, __int_as_float(bwi));
        __syncthreads();
        const float4* pq = (const float4*)&pvpi[par][0];
        float4 qa = pq[0], qb = pq[1];
        float bv = qa.x; int bi = __float_as_int(qa.y);
        if (qa.z > bv) { bv = qa.z; bi = __float_as_int(qa.w); }
        if (qb.x > bv) { bv = qb.x; bi = __float_as_int(qb.y); }
        if (qb.z > bv) { bv = qb.z; bi = __float_as_int(qb.w); }
        float2 cc = sxy[bi];
        cx = cc.x; cy = cc.y; cz = szz[bi];
        if (tid == 0) { cbx[s + 1] = cx; cby[s + 1] = cy; cbz[s + 1] = cz; }
    }
    __syncthreads();
    // single writeout of all centers (+|q|^2 for KNN)
    for (int s = tid; s < NPOINT; s += 256) {
        float x = cbx[s], y = cby[s], z = cbz[s];
        float s2 = (x * x + y * y) + z * z;   // rn, same assoc as reference
        float* o = out + b * OUTXYZ_B + 3 + s * 3;
        o[0] = x; o[1] = y; o[2] = z;
        nxyz[b * NPOINT + s] = make_float4(x, y, z, s2);
    }
}

// ---------------------------------------------------------------------------
// Fused KNN + gather + MLP(64->128->128) + maxpool. One block = 4 query rows.
// Phase 1 (KNN): wave per row, exact top-16 by (d2, idx); results in LDS.
// Phase 2 (MLP): QUARTER-SPLIT (R6 LDS-issue fix): 4 threads per channel
// pair; thread owns input quarter h4 = tid&3 and output channels {ch, ch+64}
// with ch = tid>>2, SHARING the activation reads between both channels.
// Per-thread ds_read_b128 count drops 384 -> 192 (CU LDS-pipe issue halves);
// partial sums combined with DPP quad_perm butterflies (pure VALU, no LDS
// pipe). hbuf rows padded to 144 floats so 4-quarter reads are conflict-free.
// Weights: 96 floats/thread -> no spill (R5 lesson).
// ---------------------------------------------------------------------------
template <int CTRL>
__device__ __forceinline__ float dpp_addq(float x) {
    return x + __int_as_float(__builtin_amdgcn_update_dpp(
               0, __float_as_int(x), CTRL, 0xf, 0xf, true));
}

__global__ __launch_bounds__(256)
void group_kernel(const float* __restrict__ xyz, const float* __restrict__ pts,
                  const float4* __restrict__ nxyz,
                  const float* __restrict__ w0, const float* __restrict__ b0,
                  const float* __restrict__ g0, const float* __restrict__ bt0,
                  const float* __restrict__ m0, const float* __restrict__ v0,
                  const float* __restrict__ w1, const float* __restrict__ b1,
                  const float* __restrict__ g1, const float* __restrict__ bt1,
                  const float* __restrict__ m1, const float* __restrict__ v1,
                  float* __restrict__ out)
{
    int bb = blockIdx.x, tid = threadIdx.x;
    int b = bb >> 8;                 // 256 blocks per batch
    int sbase = (bb & 255) * 4;
    __shared__ float sx[NPTS], sy[NPTS], sz[NPTS], sn[NPTS];   // 64 KB
    __shared__ float feat[16 * 64];                             // 4 KB
    __shared__ float hbuf[16 * 144];                            // 9 KB (padded)
    __shared__ int   kk_sh[4][16];

    // ---- stage xyz (+ norms) ----
    #pragma unroll 1
    for (int t = 0; t < 16; ++t) {
        int j = tid + t * 256;
        const float* p = xyz + b * XYZ_B_STRIDE + 3 + j * 3;
        float x = p[0], y = p[1], z = p[2];
        sx[j] = x; sy[j] = y; sz[j] = z;
        sn[j] = __fadd_rn(__fadd_rn(__fmul_rn(x, x), __fmul_rn(y, y)), __fmul_rn(z, z));
    }
    __syncthreads();

    // ---- phase 1: KNN (wave per row) ----
    {
        int wid = tid >> 6, lane = tid & 63;
        int r = b * NPOINT + sbase + wid;
        float4 q = nxyz[r];

        float sv[16]; int si[16];
        #pragma unroll
        for (int k = 0; k < 16; ++k) { sv[k] = 3.0e38f; si[k] = 0x7fffffff; }

        #pragma unroll 1
        for (int t = 0; t < 64; ++t) {
            int j = (t << 6) + lane;
            float dot = __fadd_rn(__fadd_rn(__fmul_rn(q.x, sx[j]), __fmul_rn(q.y, sy[j])),
                                  __fmul_rn(q.z, sz[j]));
            float d2 = __fsub_rn(__fadd_rn(q.w, sn[j]), __fmul_rn(2.0f, dot));
            if (d2 < sv[15]) {            // strict <: equal value keeps earlier index
                sv[15] = d2; si[15] = j;
                #pragma unroll
                for (int k = 15; k > 0; --k) {
                    if (sv[k] < sv[k - 1]) {
                        float tv = sv[k]; sv[k] = sv[k - 1]; sv[k - 1] = tv;
                        int   ti = si[k]; si[k] = si[k - 1]; si[k - 1] = ti;
                    }
                }
            }
        }
        // merge 64 sorted lists: 16 rounds of wave argmin over the heads
        int mykn = 0;
        #pragma unroll 1
        for (int it = 0; it < 16; ++it) {
            float bvv = sv[0]; int bii = si[0];
            #pragma unroll
            for (int off = 32; off; off >>= 1) {
                float ov = __shfl_xor(bvv, off);
                int   oi = __shfl_xor(bii, off);
                if (ov < bvv || (ov == bvv && oi < bii)) { bvv = ov; bii = oi; }
            }
            if (lane == it) mykn = bii;
            bool win = (sv[0] == bvv) && (si[0] == bii);   // idx unique -> one winner
            if (win) {
                #pragma unroll
                for (int k = 0; k < 15; ++k) { sv[k] = sv[k + 1]; si[k] = si[k + 1]; }
                sv[15] = 3.0e38f; si[15] = 0x7fffffff;
            }
        }
        if (lane < 16) kk_sh[wid][lane] = mykn;
    }
    __syncthreads();

    // ---- phase 2: MLP, quarter-split ----
    // h4 = input quarter (lane%4), ch/ch+64 = the two output channels.
    int h4 = tid & 3, ch = tid >> 2;          // ch in [0,64)
    int ch2 = ch + 64;
    float4 w0a[4], w0b[4], w1a[8], w1b[8];    // 96 floats total
    {
        const float4* pA = (const float4*)(w0 + ch  * 64 + h4 * 16);
        const float4* pB = (const float4*)(w0 + ch2 * 64 + h4 * 16);
        #pragma unroll
        for (int i = 0; i < 4; ++i) { w0a[i] = pA[i]; w0b[i] = pB[i]; }
        const float4* qA = (const float4*)(w1 + ch  * 128 + h4 * 32);
        const float4* qB = (const float4*)(w1 + ch2 * 128 + h4 * 32);
        #pragma unroll
        for (int i = 0; i < 8; ++i) { w1a[i] = qA[i]; w1b[i] = qB[i]; }
    }
    float A0a = g0[ch]  / sqrtf(v0[ch]  + 1e-5f);
    float B0a = (b0[ch]  - m0[ch])  * A0a + bt0[ch];
    float A0b = g0[ch2] / sqrtf(v0[ch2] + 1e-5f);
    float B0b = (b0[ch2] - m0[ch2]) * A0b + bt0[ch2];
    float A1a = g1[ch]  / sqrtf(v1[ch]  + 1e-5f);
    float B1a = (b1[ch]  - m1[ch])  * A1a + bt1[ch];
    float A1b = g1[ch2] / sqrtf(v1[ch2] + 1e-5f);
    float B1b = (b1[ch2] - m1[ch2]) * A1b + bt1[ch2];
    // hbuf positions for the two channels (quarter-padded layout, 36-float qtr)
    int hpA = (ch  >> 5) * 36 + (ch  & 31);
    int hpB = (ch2 >> 5) * 36 + (ch2 & 31);

    for (int row = 0; row < 4; ++row) {
        int s = sbase + row;
        float4 nq = nxyz[b * NPOINT + s];
        // gather: 4 feat elements per thread; g_xyz from staged LDS (bit-exact)
        #pragma unroll
        for (int i = 0; i < 4; ++i) {
            int e = tid + (i << 8);
            int k = e >> 6, c = e & 63;
            int j = kk_sh[row][k];
            float v;
            if (c < 3) {
                float g = (c == 0) ? sx[j] : ((c == 1) ? sy[j] : sz[j]);
                float n = (c == 0) ? nq.x : ((c == 1) ? nq.y : nq.z);
                v = __fsub_rn(g, n);
            } else {
                v = pts[(size_t)b * PTS_B_STRIDE + 61 + (size_t)j * 61 + (c - 3)];
            }
            feat[e] = v;
        }
        __syncthreads();
        // layer0: all 16 k's, my input quarter, both channels share the reads
        #pragma unroll 1
        for (int k = 0; k < 16; ++k) {
            const float4* fv = (const float4*)(feat + (k << 6) + (h4 << 4));
            float a0 = 0.f, a1 = 0.f;
            #pragma unroll
            for (int i = 0; i < 4; ++i) {
                float4 f = fv[i];
                a0 = fmaf(w0a[i].x, f.x, a0); a1 = fmaf(w0b[i].x, f.x, a1);
                a0 = fmaf(w0a[i].y, f.y, a0); a1 = fmaf(w0b[i].y, f.y, a1);
                a0 = fmaf(w0a[i].z, f.z, a0); a1 = fmaf(w0b[i].z, f.z, a1);
                a0 = fmaf(w0a[i].w, f.w, a0); a1 = fmaf(w0b[i].w, f.w, a1);
            }
            // combine 4 quarters: DPP quad_perm butterflies (pure VALU)
            a0 = dpp_addq<0x4E>(dpp_addq<0xB1>(a0));
            a1 = dpp_addq<0x4E>(dpp_addq<0xB1>(a1));
            if (h4 == 0) {
                hbuf[k * 144 + hpA] = fmaxf(a0 * A0a + B0a, 0.f);
                hbuf[k * 144 + hpB] = fmaxf(a1 * A0b + B0b, 0.f);
            }
        }
        __syncthreads();
        // layer1 + max over all 16 k's, my input quarter, both channels
        float mx0 = 0.f, mx1 = 0.f;     // relu outputs >= 0
        #pragma unroll 1
        for (int k = 0; k < 16; ++k) {
            const float4* hv = (const float4*)(hbuf + k * 144 + h4 * 36);
            float a0 = 0.f, a1 = 0.f;
            #pragma unroll
            for (int i = 0; i < 8; ++i) {
                float4 f = hv[i];
                a0 = fmaf(w1a[i].x, f.x, a0); a1 = fmaf(w1b[i].x, f.x, a1);
                a0 = fmaf(w1a[i].y, f.y, a0); a1 = fmaf(w1b[i].y, f.y, a1);
                a0 = fmaf(w1a[i].z, f.z, a0); a1 = fmaf(w1b[i].z, f.z, a1);
                a0 = fmaf(w1a[i].w, f.w, a0); a1 = fmaf(w1b[i].w, f.w, a1);
            }
            a0 = dpp_addq<0x4E>(dpp_addq<0xB1>(a0));
            a1 = dpp_addq<0x4E>(dpp_addq<0xB1>(a1));
            mx0 = fmaxf(mx0, fmaxf(a0 * A1a + B1a, 0.f));
            mx1 = fmaxf(mx1, fmaxf(a1 * A1b + B1b, 0.f));
        }
        if (h4 == 0) {
            size_t ob = OUT_PTS_OFF + (size_t)b * OUTPTS_B + (size_t)(1 + s) * 128;
            out[ob + ch]  = mx0;
            out[ob + ch2] = mx1;
        }
        __syncthreads();   // protect feat/hbuf before next row overwrites
    }
}

// ---------------------------------------------------------------------------
extern "C" void kernel_launch(void* const* d_in, const int* in_sizes, int n_in,
                              void* d_out, int out_size, void* d_ws, size_t ws_size,
                              hipStream_t stream) {
    const float* xyz = (const float*)d_in[0];
    const float* pts = (const float*)d_in[1];
    // dict order: sa0 block, cls0 block, sa1 block, cls1 block
    const float* sa_w0 = (const float*)d_in[2];
    const float* sa_b0 = (const float*)d_in[3];
    const float* sa_g0 = (const float*)d_in[4];
    const float* sa_bt0 = (const float*)d_in[5];
    const float* sa_m0 = (const float*)d_in[6];
    const float* sa_v0 = (const float*)d_in[7];
    const float* cls_w0 = (const float*)d_in[8];
    const float* cls_b0 = (const float*)d_in[9];
    const float* cls_g0 = (const float*)d_in[10];
    const float* cls_bt0 = (const float*)d_in[11];
    const float* cls_m0 = (const float*)d_in[12];
    const float* cls_v0 = (const float*)d_in[13];
    const float* sa_w1 = (const float*)d_in[14];
    const float* sa_b1 = (const float*)d_in[15];
    const float* sa_g1 = (const float*)d_in[16];
    const float* sa_bt1 = (const float*)d_in[17];
    const float* sa_m1 = (const float*)d_in[18];
    const float* sa_v1 = (const float*)d_in[19];
    const float* cls_w1 = (const float*)d_in[20];
    const float* cls_b1 = (const float*)d_in[21];
    const float* cls_g1 = (const float*)d_in[22];
    const float* cls_bt1 = (const float*)d_in[23];
    const float* cls_m1 = (const float*)d_in[24];
    const float* cls_v1 = (const float*)d_in[25];

    float* out = (float*)d_out;
    float4* nxyz_ws = (float4*)d_ws;                          // 8192 * 16 B

    cls_kernel<<<NB, 128, 0, stream>>>(xyz, pts,
        cls_w0, cls_b0, cls_g0, cls_bt0, cls_m0, cls_v0,
        cls_w1, cls_b1, cls_g1, cls_bt1, cls_m1, cls_v1, out);
    fps_kernel<<<NB, 256, 0, stream>>>(xyz, nxyz_ws, out);
    group_kernel<<<NB * (NPOINT / 4), 256, 0, stream>>>(xyz, pts, nxyz_ws,
        sa_w0, sa_b0, sa_g0, sa_bt0, sa_m0, sa_v0,
        sa_w1, sa_b1, sa_g1, sa_bt1, sa_m1, sa_v1, out);
}

// Round 9
// 951.725 us; speedup vs baseline: 2.2772x; 1.1521x over previous
//
#include <hip/hip_runtime.h>
#include <math.h>

// Problem geometry (B=8, N=4097, D=61, NPOINT=1024, NSAMPLE=16)
#define NB 8
#define NALL 4097
#define NPTS 4096            // N-1 points used for FPS/KNN
#define ND 61
#define NPOINT 1024
#define NS 16
#define XYZ_B_STRIDE 12291   // 4097*3
#define PTS_B_STRIDE 249917  // 4097*61
#define OUTXYZ_B 3075        // 1025*3
#define OUTPTS_B 131200      // 1025*128
#define OUT_PTS_OFF 24600    // 8*1025*3  (out_xyz block precedes out_pts)

// ---------------------------------------------------------------------------
// Fused producer-consumer kernel.
//   blocks [0,8):   FPS producer, one per batch (R2/R8 structure, 634 us),
//                   + 16-row incremental flush to nxyz_ws/out + release-
//                   publish of progress. setprio(3): protect the serial
//                   critical path from co-resident consumer waves.
//   blocks [8,16):  cls branch (one per batch).
//   blocks [16,..): group tiles: KNN + gather + MLP + maxpool for 4 rows.
//                   tile -> (b = tile&7, sbase = (tile>>3)*4) so consumption
//                   order tracks production across all 8 batches; tid0
//                   acquire-polls progress before the KNN phase.
// LDS overlaid via union: 79 KB -> 2 blocks/CU.
// Sync: d_ws progress ints are 0xAA-poisoned (negative) each launch; fps
// publishes s (rows < s ready) with agent-scope release; consumers
// acquire-load + __syncthreads. Flush reads cb rows <= s-1 only (one-barrier
// separation from tid0's cb writes -> race-free).
// ---------------------------------------------------------------------------
struct FpsShared {
    float2 sxy[NPTS];                         // 32 KB
    float  szz[NPTS];                         // 16 KB
    float  cbx[NPOINT], cby[NPOINT], cbz[NPOINT];  // 12 KB
    alignas(16) float2 pvpi[2][4];
};
struct GrpShared {
    float sx[NPTS], sy[NPTS], sz[NPTS], sn[NPTS];  // 64 KB
    float feat[16 * 64];                      // 4 KB
    float hbuf[16 * 144];                     // 9 KB (quarter-padded)
    int   kk[4][16];
};
struct ClsShared {
    float in64[64];
    float h[128];
};
union SMemU { FpsShared f; GrpShared g; ClsShared c; };

#define DPP_MAXSTEP(x, ctrl)                                                   \
    x = fmaxf(x, __int_as_float(__builtin_amdgcn_update_dpp(                   \
            0, __float_as_int(x), ctrl, 0xf, 0xf, true)))

template <int CTRL>
__device__ __forceinline__ float dpp_addq(float x) {
    return x + __int_as_float(__builtin_amdgcn_update_dpp(
               0, __float_as_int(x), CTRL, 0xf, 0xf, true));
}

__global__ __launch_bounds__(256)
void fused_kernel(const float* __restrict__ xyz, const float* __restrict__ pts,
                  const float* __restrict__ sw0, const float* __restrict__ sb0,
                  const float* __restrict__ sg0, const float* __restrict__ sbt0,
                  const float* __restrict__ sm0, const float* __restrict__ sv0,
                  const float* __restrict__ sw1, const float* __restrict__ sb1,
                  const float* __restrict__ sg1, const float* __restrict__ sbt1,
                  const float* __restrict__ sm1, const float* __restrict__ sv1,
                  const float* __restrict__ cw0, const float* __restrict__ cb0,
                  const float* __restrict__ cg0, const float* __restrict__ cbt0,
                  const float* __restrict__ cm0, const float* __restrict__ cv0,
                  const float* __restrict__ cw1, const float* __restrict__ cb1,
                  const float* __restrict__ cg1, const float* __restrict__ cbt1,
                  const float* __restrict__ cm1, const float* __restrict__ cv1,
                  float4* __restrict__ nxyz, int* __restrict__ prog,
                  float* __restrict__ out)
{
    __shared__ SMemU u;
    int bb = blockIdx.x, tid = threadIdx.x;

    if (bb < NB) {
        // =================== FPS producer (batch bb) ======================
#pragma clang fp contract(off)
        __builtin_amdgcn_s_setprio(3);        // protect serial critical path
        int b = bb;
        float2 px[8], py[8], pz[8], dist[8];
        #pragma unroll
        for (int t = 0; t < 8; ++t) {
            int j = tid * 16 + t * 2;
            const float* p = xyz + b * XYZ_B_STRIDE + 3 + j * 3;  // xyz[:,1:]
            float x0 = p[0], y0 = p[1], z0 = p[2];
            float x1 = p[3], y1 = p[4], z1 = p[5];
            px[t] = make_float2(x0, x1);
            py[t] = make_float2(y0, y1);
            pz[t] = make_float2(z0, z1);
            dist[t] = make_float2(1e10f, 1e10f);
            u.f.sxy[j]     = make_float2(x0, y0);
            u.f.sxy[j + 1] = make_float2(x1, y1);
            u.f.szz[j] = z0; u.f.szz[j + 1] = z1;
        }
        __syncthreads();
        float2 c0 = u.f.sxy[0];
        float cx = c0.x, cy = c0.y, cz = u.f.szz[0];  // far_0 = 0
        if (tid == 0) { u.f.cbx[0] = cx; u.f.cby[0] = cy; u.f.cbz[0] = cz; }

        for (int s = 0; s < NPOINT - 1; ++s) {
            // incremental flush: rows [s-16, s-1] (all cb writes of these
            // rows are >=1 barrier old -> race-free). wave1 does it; others
            // proceed straight into the update phase.
            if ((s & 15) == 0 && s > 0) {
                if (tid >= 64 && tid < 80) {
                    int row = s - 16 + (tid - 64);
                    float x = u.f.cbx[row], y = u.f.cby[row], z = u.f.cbz[row];
                    float* o = out + b * OUTXYZ_B + 3 + row * 3;
                    o[0] = x; o[1] = y; o[2] = z;
                    float s2 = (x * x + y * y) + z * z;  // rn, ref assoc
                    nxyz[b * NPOINT + row] = make_float4(x, y, z, s2);
                }
                if (tid == 64)   // release: drains wave1's stores (same wave)
                    __hip_atomic_store(prog + b * 16, s, __ATOMIC_RELEASE,
                                       __HIP_MEMORY_SCOPE_AGENT);
            }
            float nd[16];
            #pragma unroll
            for (int t = 0; t < 8; ++t) {
                float dx0 = px[t].x - cx, dx1 = px[t].y - cx;
                float dy0 = py[t].x - cy, dy1 = py[t].y - cy;
                float dz0 = pz[t].x - cz, dz1 = pz[t].y - cz;
                float d0 = (dx0 * dx0 + dy0 * dy0) + dz0 * dz0;
                float d1 = (dx1 * dx1 + dy1 * dy1) + dz1 * dz1;
                float n0 = fminf(dist[t].x, d0);
                float n1 = fminf(dist[t].y, d1);
                dist[t] = make_float2(n0, n1);
                nd[t * 2] = n0; nd[t * 2 + 1] = n1;
            }
            float g0 = fmaxf(fmaxf(nd[0], nd[1]), nd[2]);
            float g1 = fmaxf(fmaxf(nd[3], nd[4]), nd[5]);
            float g2 = fmaxf(fmaxf(nd[6], nd[7]), nd[8]);
            float g3 = fmaxf(fmaxf(nd[9], nd[10]), nd[11]);
            float g4 = fmaxf(fmaxf(nd[12], nd[13]), nd[14]);
            float h0 = fmaxf(fmaxf(g0, g1), g2);
            float h1 = fmaxf(fmaxf(g3, g4), nd[15]);
            float lmax = fmaxf(h0, h1);
            unsigned msk = 0;
            #pragma unroll
            for (int t = 0; t < 16; ++t) msk |= (nd[t] == lmax) ? (1u << t) : 0u;
            int mymi = (tid << 4) + (__ffs(msk) - 1);
            float red = lmax;
            DPP_MAXSTEP(red, 0x111);
            DPP_MAXSTEP(red, 0x112);
            DPP_MAXSTEP(red, 0x114);
            DPP_MAXSTEP(red, 0x118);
            DPP_MAXSTEP(red, 0x142);
            DPP_MAXSTEP(red, 0x143);   // lane 63 has wave max
            float wmax = __int_as_float(
                __builtin_amdgcn_readlane(__float_as_int(red), 63));
            unsigned long long ball = __ballot(lmax == wmax);
            int first = __ffsll((long long)ball) - 1;
            int bwi = __builtin_amdgcn_readlane(mymi, first);
            int par = s & 1;
            if ((tid & 63) == 0)
                u.f.pvpi[par][tid >> 6] = make_float2(wmax, __int_as_float(bwi));
            __syncthreads();
            const float4* pq = (const float4*)&u.f.pvpi[par][0];
            float4 qa = pq[0], qb = pq[1];
            float bv = qa.x; int bi = __float_as_int(qa.y);
            if (qa.z > bv) { bv = qa.z; bi = __float_as_int(qa.w); }
            if (qb.x > bv) { bv = qb.x; bi = __float_as_int(qb.y); }
            if (qb.z > bv) { bv = qb.z; bi = __float_as_int(qb.w); }
            float2 cc = u.f.sxy[bi];
            cx = cc.x; cy = cc.y; cz = u.f.szz[bi];
            if (tid == 0) { u.f.cbx[s + 1] = cx; u.f.cby[s + 1] = cy; u.f.cbz[s + 1] = cz; }
        }
        __syncthreads();   // make cb[1023] visible
        if (tid < 16) {
            int row = NPOINT - 16 + tid;   // rows 1008..1023
            float x = u.f.cbx[row], y = u.f.cby[row], z = u.f.cbz[row];
            float* o = out + b * OUTXYZ_B + 3 + row * 3;
            o[0] = x; o[1] = y; o[2] = z;
            float s2 = (x * x + y * y) + z * z;
            nxyz[b * NPOINT + row] = make_float4(x, y, z, s2);
        }
        if (tid == 0)
            __hip_atomic_store(prog + b * 16, NPOINT, __ATOMIC_RELEASE,
                               __HIP_MEMORY_SCOPE_AGENT);
    } else if (bb < 2 * NB) {
        // =================== cls branch (batch bb-8) ======================
        int b = bb - NB, t = tid;
        if (t < 64)
            u.c.in64[t] = (t < 3) ? xyz[b * XYZ_B_STRIDE + t]
                                  : pts[(size_t)b * PTS_B_STRIDE + (t - 3)];
        __syncthreads();
        if (t < 128) {
            float A = cg0[t] / sqrtf(cv0[t] + 1e-5f);
            float B = (cb0[t] - cm0[t]) * A + cbt0[t];
            float acc = 0.f;
            for (int c = 0; c < 64; ++c) acc = fmaf(cw0[t * 64 + c], u.c.in64[c], acc);
            u.c.h[t] = fmaxf(acc * A + B, 0.f);
        }
        __syncthreads();
        if (t < 128) {
            float A = cg1[t] / sqrtf(cv1[t] + 1e-5f);
            float B = (cb1[t] - cm1[t]) * A + cbt1[t];
            float acc = 0.f;
            for (int c = 0; c < 128; ++c) acc = fmaf(cw1[t * 128 + c], u.c.h[c], acc);
            out[OUT_PTS_OFF + (size_t)b * OUTPTS_B + t] = fmaxf(acc * A + B, 0.f);
        }
        if (t < 3) out[b * OUTXYZ_B + t] = xyz[b * XYZ_B_STRIDE + t];
    } else {
        // ============== group tile: KNN + gather + MLP + maxpool ==========
        int tile = bb - 2 * NB;
        int b = tile & 7;                  // consumption tracks production
        int sbase = (tile >> 3) * 4;

        // ---- stage xyz (+ norms) — overlaps the producer wait ----
        #pragma unroll 1
        for (int t = 0; t < 16; ++t) {
            int j = tid + t * 256;
            const float* p = xyz + b * XYZ_B_STRIDE + 3 + j * 3;
            float x = p[0], y = p[1], z = p[2];
            u.g.sx[j] = x; u.g.sy[j] = y; u.g.sz[j] = z;
            u.g.sn[j] = __fadd_rn(__fadd_rn(__fmul_rn(x, x), __fmul_rn(y, y)),
                                  __fmul_rn(z, z));
        }
        // ---- wait for producer: rows < sbase+4 published ----
        if (tid == 0) {
            while (__hip_atomic_load(prog + b * 16, __ATOMIC_ACQUIRE,
                                     __HIP_MEMORY_SCOPE_AGENT) < sbase + 4)
                __builtin_amdgcn_s_sleep(8);
        }
        __syncthreads();

        // ---- phase 1: KNN (wave per row) ----
        {
            int wid = tid >> 6, lane = tid & 63;
            int r = b * NPOINT + sbase + wid;
            float4 q = nxyz[r];

            float sv[16]; int si[16];
            #pragma unroll
            for (int k = 0; k < 16; ++k) { sv[k] = 3.0e38f; si[k] = 0x7fffffff; }

            #pragma unroll 1
            for (int t = 0; t < 64; ++t) {
                int j = (t << 6) + lane;
                float dot = __fadd_rn(__fadd_rn(__fmul_rn(q.x, u.g.sx[j]),
                                                __fmul_rn(q.y, u.g.sy[j])),
                                      __fmul_rn(q.z, u.g.sz[j]));
                float d2 = __fsub_rn(__fadd_rn(q.w, u.g.sn[j]), __fmul_rn(2.0f, dot));
                if (d2 < sv[15]) {        // strict <: equal keeps earlier index
                    sv[15] = d2; si[15] = j;
                    #pragma unroll
                    for (int k = 15; k > 0; --k) {
                        if (sv[k] < sv[k - 1]) {
                            float tv = sv[k]; sv[k] = sv[k - 1]; sv[k - 1] = tv;
                            int   ti = si[k]; si[k] = si[k - 1]; si[k - 1] = ti;
                        }
                    }
                }
            }
            int mykn = 0;
            #pragma unroll 1
            for (int it = 0; it < 16; ++it) {
                float bvv = sv[0]; int bii = si[0];
                #pragma unroll
                for (int off = 32; off; off >>= 1) {
                    float ov = __shfl_xor(bvv, off);
                    int   oi = __shfl_xor(bii, off);
                    if (ov < bvv || (ov == bvv && oi < bii)) { bvv = ov; bii = oi; }
                }
                if (lane == it) mykn = bii;
                bool win = (sv[0] == bvv) && (si[0] == bii);
                if (win) {
                    #pragma unroll
                    for (int k = 0; k < 15; ++k) { sv[k] = sv[k + 1]; si[k] = si[k + 1]; }
                    sv[15] = 3.0e38f; si[15] = 0x7fffffff;
                }
            }
            if (lane < 16) u.g.kk[wid][lane] = mykn;
        }
        __syncthreads();

        // ---- phase 2: MLP, quarter-split ----
        int h4 = tid & 3, ch = tid >> 2;      // ch in [0,64)
        int ch2 = ch + 64;
        float4 w0a[4], w0b[4], w1a[8], w1b[8];
        {
            const float4* pA = (const float4*)(sw0 + ch  * 64 + h4 * 16);
            const float4* pB = (const float4*)(sw0 + ch2 * 64 + h4 * 16);
            #pragma unroll
            for (int i = 0; i < 4; ++i) { w0a[i] = pA[i]; w0b[i] = pB[i]; }
            const float4* qA = (const float4*)(sw1 + ch  * 128 + h4 * 32);
            const float4* qB = (const float4*)(sw1 + ch2 * 128 + h4 * 32);
            #pragma unroll
            for (int i = 0; i < 8; ++i) { w1a[i] = qA[i]; w1b[i] = qB[i]; }
        }
        float A0a = sg0[ch]  / sqrtf(sv0[ch]  + 1e-5f);
        float B0a = (sb0[ch]  - sm0[ch])  * A0a + sbt0[ch];
        float A0b = sg0[ch2] / sqrtf(sv0[ch2] + 1e-5f);
        float B0b = (sb0[ch2] - sm0[ch2]) * A0b + sbt0[ch2];
        float A1a = sg1[ch]  / sqrtf(sv1[ch]  + 1e-5f);
        float B1a = (sb1[ch]  - sm1[ch])  * A1a + sbt1[ch];
        float A1b = sg1[ch2] / sqrtf(sv1[ch2] + 1e-5f);
        float B1b = (sb1[ch2] - sm1[ch2]) * A1b + sbt1[ch2];
        int hpA = (ch  >> 5) * 36 + (ch  & 31);
        int hpB = (ch2 >> 5) * 36 + (ch2 & 31);

        for (int row = 0; row < 4; ++row) {
            int s = sbase + row;
            float4 nq = nxyz[b * NPOINT + s];
            #pragma unroll
            for (int i = 0; i < 4; ++i) {
                int e = tid + (i << 8);
                int k = e >> 6, c = e & 63;
                int j = u.g.kk[row][k];
                float v;
                if (c < 3) {
                    float g = (c == 0) ? u.g.sx[j] : ((c == 1) ? u.g.sy[j] : u.g.sz[j]);
                    float n = (c == 0) ? nq.x : ((c == 1) ? nq.y : nq.z);
                    v = __fsub_rn(g, n);
                } else {
                    v = pts[(size_t)b * PTS_B_STRIDE + 61 + (size_t)j * 61 + (c - 3)];
                }
                u.g.feat[e] = v;
            }
            __syncthreads();
            #pragma unroll 1
            for (int k = 0; k < 16; ++k) {
                const float4* fv = (const float4*)(u.g.feat + (k << 6) + (h4 << 4));
                float a0 = 0.f, a1 = 0.f;
                #pragma unroll
                for (int i = 0; i < 4; ++i) {
                    float4 f = fv[i];
                    a0 = fmaf(w0a[i].x, f.x, a0); a1 = fmaf(w0b[i].x, f.x, a1);
                    a0 = fmaf(w0a[i].y, f.y, a0); a1 = fmaf(w0b[i].y, f.y, a1);
                    a0 = fmaf(w0a[i].z, f.z, a0); a1 = fmaf(w0b[i].z, f.z, a1);
                    a0 = fmaf(w0a[i].w, f.w, a0); a1 = fmaf(w0b[i].w, f.w, a1);
                }
                a0 = dpp_addq<0x4E>(dpp_addq<0xB1>(a0));
                a1 = dpp_addq<0x4E>(dpp_addq<0xB1>(a1));
                if (h4 == 0) {
                    u.g.hbuf[k * 144 + hpA] = fmaxf(a0 * A0a + B0a, 0.f);
                    u.g.hbuf[k * 144 + hpB] = fmaxf(a1 * A0b + B0b, 0.f);
                }
            }
            __syncthreads();
            float mx0 = 0.f, mx1 = 0.f;
            #pragma unroll 1
            for (int k = 0; k < 16; ++k) {
                const float4* hv = (const float4*)(u.g.hbuf + k * 144 + h4 * 36);
                float a0 = 0.f, a1 = 0.f;
                #pragma unroll
                for (int i = 0; i < 8; ++i) {
                    float4 f = hv[i];
                    a0 = fmaf(w1a[i].x, f.x, a0); a1 = fmaf(w1b[i].x, f.x, a1);
                    a0 = fmaf(w1a[i].y, f.y, a0); a1 = fmaf(w1b[i].y, f.y, a1);
                    a0 = fmaf(w1a[i].z, f.z, a0); a1 = fmaf(w1b[i].z, f.z, a1);
                    a0 = fmaf(w1a[i].w, f.w, a0); a1 = fmaf(w1b[i].w, f.w, a1);
                }
                a0 = dpp_addq<0x4E>(dpp_addq<0xB1>(a0));
                a1 = dpp_addq<0x4E>(dpp_addq<0xB1>(a1));
                mx0 = fmaxf(mx0, fmaxf(a0 * A1a + B1a, 0.f));
                mx1 = fmaxf(mx1, fmaxf(a1 * A1b + B1b, 0.f));
            }
            if (h4 == 0) {
                size_t ob = OUT_PTS_OFF + (size_t)b * OUTPTS_B + (size_t)(1 + s) * 128;
                out[ob + ch]  = mx0;
                out[ob + ch2] = mx1;
            }
            __syncthreads();
        }
    }
}

// ---------------------------------------------------------------------------
extern "C" void kernel_launch(void* const* d_in, const int* in_sizes, int n_in,
                              void* d_out, int out_size, void* d_ws, size_t ws_size,
                              hipStream_t stream) {
    const float* xyz = (const float*)d_in[0];
    const float* pts = (const float*)d_in[1];
    // dict order: sa0 block, cls0 block, sa1 block, cls1 block
    const float* sa_w0 = (const float*)d_in[2];
    const float* sa_b0 = (const float*)d_in[3];
    const float* sa_g0 = (const float*)d_in[4];
    const float* sa_bt0 = (const float*)d_in[5];
    const float* sa_m0 = (const float*)d_in[6];
    const float* sa_v0 = (const float*)d_in[7];
    const float* cls_w0 = (const float*)d_in[8];
    const float* cls_b0 = (const float*)d_in[9];
    const float* cls_g0 = (const float*)d_in[10];
    const float* cls_bt0 = (const float*)d_in[11];
    const float* cls_m0 = (const float*)d_in[12];
    const float* cls_v0 = (const float*)d_in[13];
    const float* sa_w1 = (const float*)d_in[14];
    const float* sa_b1 = (const float*)d_in[15];
    const float* sa_g1 = (const float*)d_in[16];
    const float* sa_bt1 = (const float*)d_in[17];
    const float* sa_m1 = (const float*)d_in[18];
    const float* sa_v1 = (const float*)d_in[19];
    const float* cls_w1 = (const float*)d_in[20];
    const float* cls_b1 = (const float*)d_in[21];
    const float* cls_g1 = (const float*)d_in[22];
    const float* cls_bt1 = (const float*)d_in[23];
    const float* cls_m1 = (const float*)d_in[24];
    const float* cls_v1 = (const float*)d_in[25];

    float* out = (float*)d_out;
    float4* nxyz_ws = (float4*)d_ws;                          // 8192 * 16 B
    int* prog = (int*)((char*)d_ws + NB * NPOINT * sizeof(float4));  // 8 slots, 64B apart

    int grid = 2 * NB + NB * (NPOINT / 4);    // 8 fps + 8 cls + 2048 tiles
    fused_kernel<<<grid, 256, 0, stream>>>(xyz, pts,
        sa_w0, sa_b0, sa_g0, sa_bt0, sa_m0, sa_v0,
        sa_w1, sa_b1, sa_g1, sa_bt1, sa_m1, sa_v1,
        cls_w0, cls_b0, cls_g0, cls_bt0, cls_m0, cls_v0,
        cls_w1, cls_b1, cls_g1, cls_bt1, cls_m1, cls_v1,
        nxyz_ws, prog, out);
}

// Round 10
// 895.896 us; speedup vs baseline: 2.4191x; 1.0623x over previous
//
#include <hip/hip_runtime.h>
#include <math.h>

// Problem geometry (B=8, N=4097, D=61, NPOINT=1024, NSAMPLE=16)
#define NB 8
#define NALL 4097
#define NPTS 4096            // N-1 points used for FPS/KNN
#define ND 61
#define NPOINT 1024
#define NS 16
#define XYZ_B_STRIDE 12291   // 4097*3
#define PTS_B_STRIDE 249917  // 4097*61
#define OUTXYZ_B 3075        // 1025*3
#define OUTPTS_B 131200      // 1025*128
#define OUT_PTS_OFF 24600    // 8*1025*3  (out_xyz block precedes out_pts)

// ---------------------------------------------------------------------------
// Fused producer-consumer kernel (R9 structure) + R10 change: the shared-mem
// union is padded to 88 KB so occupancy is 1 block/CU. This makes the 8 FPS
// producer blocks EXCLUSIVE owners of their CUs: in R9 (77.5 KB -> 2 blk/CU)
// a consumer block co-resided with each producer and its ds_read_b128
// streams contended the CU's single LDS pipe, adding ~256 us to the serial
// FPS critical path (890 measured vs 634 standalone). setprio can't fix
// LDS-pipe contention; occupancy isolation can.
// ---------------------------------------------------------------------------
struct FpsShared {
    float2 sxy[NPTS];                         // 32 KB
    float  szz[NPTS];                         // 16 KB
    float  cbx[NPOINT], cby[NPOINT], cbz[NPOINT];  // 12 KB
    alignas(16) float2 pvpi[2][4];
};
struct GrpShared {
    float sx[NPTS], sy[NPTS], sz[NPTS], sn[NPTS];  // 64 KB
    float feat[16 * 64];                      // 4 KB
    float hbuf[16 * 144];                     // 9 KB (quarter-padded)
    int   kk[4][16];
};
struct ClsShared {
    float in64[64];
    float h[128];
};
union SMemU {
    FpsShared f; GrpShared g; ClsShared c;
    float pad_force_single_block[22528];      // 88 KB -> 1 block/CU
};

#define DPP_MAXSTEP(x, ctrl)                                                   \
    x = fmaxf(x, __int_as_float(__builtin_amdgcn_update_dpp(                   \
            0, __float_as_int(x), ctrl, 0xf, 0xf, true)))

template <int CTRL>
__device__ __forceinline__ float dpp_addq(float x) {
    return x + __int_as_float(__builtin_amdgcn_update_dpp(
               0, __float_as_int(x), CTRL, 0xf, 0xf, true));
}

__global__ __launch_bounds__(256)
void fused_kernel(const float* __restrict__ xyz, const float* __restrict__ pts,
                  const float* __restrict__ sw0, const float* __restrict__ sb0,
                  const float* __restrict__ sg0, const float* __restrict__ sbt0,
                  const float* __restrict__ sm0, const float* __restrict__ sv0,
                  const float* __restrict__ sw1, const float* __restrict__ sb1,
                  const float* __restrict__ sg1, const float* __restrict__ sbt1,
                  const float* __restrict__ sm1, const float* __restrict__ sv1,
                  const float* __restrict__ cw0, const float* __restrict__ cb0,
                  const float* __restrict__ cg0, const float* __restrict__ cbt0,
                  const float* __restrict__ cm0, const float* __restrict__ cv0,
                  const float* __restrict__ cw1, const float* __restrict__ cb1,
                  const float* __restrict__ cg1, const float* __restrict__ cbt1,
                  const float* __restrict__ cm1, const float* __restrict__ cv1,
                  float4* __restrict__ nxyz, int* __restrict__ prog,
                  float* __restrict__ out)
{
    __shared__ SMemU u;
    int bb = blockIdx.x, tid = threadIdx.x;

    if (bb < NB) {
        // =================== FPS producer (batch bb) ======================
#pragma clang fp contract(off)
        __builtin_amdgcn_s_setprio(3);        // protect serial critical path
        int b = bb;
        float2 px[8], py[8], pz[8], dist[8];
        #pragma unroll
        for (int t = 0; t < 8; ++t) {
            int j = tid * 16 + t * 2;
            const float* p = xyz + b * XYZ_B_STRIDE + 3 + j * 3;  // xyz[:,1:]
            float x0 = p[0], y0 = p[1], z0 = p[2];
            float x1 = p[3], y1 = p[4], z1 = p[5];
            px[t] = make_float2(x0, x1);
            py[t] = make_float2(y0, y1);
            pz[t] = make_float2(z0, z1);
            dist[t] = make_float2(1e10f, 1e10f);
            u.f.sxy[j]     = make_float2(x0, y0);
            u.f.sxy[j + 1] = make_float2(x1, y1);
            u.f.szz[j] = z0; u.f.szz[j + 1] = z1;
        }
        __syncthreads();
        float2 c0 = u.f.sxy[0];
        float cx = c0.x, cy = c0.y, cz = u.f.szz[0];  // far_0 = 0
        if (tid == 0) { u.f.cbx[0] = cx; u.f.cby[0] = cy; u.f.cbz[0] = cz; }

        for (int s = 0; s < NPOINT - 1; ++s) {
            // incremental flush: rows [s-16, s-1] (cb writes of these rows
            // are >=1 barrier old -> race-free). wave1 handles it.
            if ((s & 15) == 0 && s > 0) {
                if (tid >= 64 && tid < 80) {
                    int row = s - 16 + (tid - 64);
                    float x = u.f.cbx[row], y = u.f.cby[row], z = u.f.cbz[row];
                    float* o = out + b * OUTXYZ_B + 3 + row * 3;
                    o[0] = x; o[1] = y; o[2] = z;
                    float s2 = (x * x + y * y) + z * z;  // rn, ref assoc
                    nxyz[b * NPOINT + row] = make_float4(x, y, z, s2);
                }
                if (tid == 64)   // release: drains wave1's stores (same wave)
                    __hip_atomic_store(prog + b * 16, s, __ATOMIC_RELEASE,
                                       __HIP_MEMORY_SCOPE_AGENT);
            }
            float nd[16];
            #pragma unroll
            for (int t = 0; t < 8; ++t) {
                float dx0 = px[t].x - cx, dx1 = px[t].y - cx;
                float dy0 = py[t].x - cy, dy1 = py[t].y - cy;
                float dz0 = pz[t].x - cz, dz1 = pz[t].y - cz;
                float d0 = (dx0 * dx0 + dy0 * dy0) + dz0 * dz0;
                float d1 = (dx1 * dx1 + dy1 * dy1) + dz1 * dz1;
                float n0 = fminf(dist[t].x, d0);
                float n1 = fminf(dist[t].y, d1);
                dist[t] = make_float2(n0, n1);
                nd[t * 2] = n0; nd[t * 2 + 1] = n1;
            }
            float g0 = fmaxf(fmaxf(nd[0], nd[1]), nd[2]);
            float g1 = fmaxf(fmaxf(nd[3], nd[4]), nd[5]);
            float g2 = fmaxf(fmaxf(nd[6], nd[7]), nd[8]);
            float g3 = fmaxf(fmaxf(nd[9], nd[10]), nd[11]);
            float g4 = fmaxf(fmaxf(nd[12], nd[13]), nd[14]);
            float h0 = fmaxf(fmaxf(g0, g1), g2);
            float h1 = fmaxf(fmaxf(g3, g4), nd[15]);
            float lmax = fmaxf(h0, h1);
            unsigned msk = 0;
            #pragma unroll
            for (int t = 0; t < 16; ++t) msk |= (nd[t] == lmax) ? (1u << t) : 0u;
            int mymi = (tid << 4) + (__ffs(msk) - 1);
            float red = lmax;
            DPP_MAXSTEP(red, 0x111);
            DPP_MAXSTEP(red, 0x112);
            DPP_MAXSTEP(red, 0x114);
            DPP_MAXSTEP(red, 0x118);
            DPP_MAXSTEP(red, 0x142);
            DPP_MAXSTEP(red, 0x143);   // lane 63 has wave max
            float wmax = __int_as_float(
                __builtin_amdgcn_readlane(__float_as_int(red), 63));
            unsigned long long ball = __ballot(lmax == wmax);
            int first = __ffsll((long long)ball) - 1;
            int bwi = __builtin_amdgcn_readlane(mymi, first);
            int par = s & 1;
            if ((tid & 63) == 0)
                u.f.pvpi[par][tid >> 6] = make_float2(wmax, __int_as_float(bwi));
            __syncthreads();
            const float4* pq = (const float4*)&u.f.pvpi[par][0];
            float4 qa = pq[0], qb = pq[1];
            float bv = qa.x; int bi = __float_as_int(qa.y);
            if (qa.z > bv) { bv = qa.z; bi = __float_as_int(qa.w); }
            if (qb.x > bv) { bv = qb.x; bi = __float_as_int(qb.y); }
            if (qb.z > bv) { bv = qb.z; bi = __float_as_int(qb.w); }
            float2 cc = u.f.sxy[bi];
            cx = cc.x; cy = cc.y; cz = u.f.szz[bi];
            if (tid == 0) { u.f.cbx[s + 1] = cx; u.f.cby[s + 1] = cy; u.f.cbz[s + 1] = cz; }
        }
        __syncthreads();   // make cb[1023] visible
        if (tid < 16) {
            int row = NPOINT - 16 + tid;   // rows 1008..1023
            float x = u.f.cbx[row], y = u.f.cby[row], z = u.f.cbz[row];
            float* o = out + b * OUTXYZ_B + 3 + row * 3;
            o[0] = x; o[1] = y; o[2] = z;
            float s2 = (x * x + y * y) + z * z;
            nxyz[b * NPOINT + row] = make_float4(x, y, z, s2);
        }
        if (tid == 0)
            __hip_atomic_store(prog + b * 16, NPOINT, __ATOMIC_RELEASE,
                               __HIP_MEMORY_SCOPE_AGENT);
    } else if (bb < 2 * NB) {
        // =================== cls branch (batch bb-8) ======================
        int b = bb - NB, t = tid;
        if (t < 64)
            u.c.in64[t] = (t < 3) ? xyz[b * XYZ_B_STRIDE + t]
                                  : pts[(size_t)b * PTS_B_STRIDE + (t - 3)];
        __syncthreads();
        if (t < 128) {
            float A = cg0[t] / sqrtf(cv0[t] + 1e-5f);
            float B = (cb0[t] - cm0[t]) * A + cbt0[t];
            float acc = 0.f;
            for (int c = 0; c < 64; ++c) acc = fmaf(cw0[t * 64 + c], u.c.in64[c], acc);
            u.c.h[t] = fmaxf(acc * A + B, 0.f);
        }
        __syncthreads();
        if (t < 128) {
            float A = cg1[t] / sqrtf(cv1[t] + 1e-5f);
            float B = (cb1[t] - cm1[t]) * A + cbt1[t];
            float acc = 0.f;
            for (int c = 0; c < 128; ++c) acc = fmaf(cw1[t * 128 + c], u.c.h[c], acc);
            out[OUT_PTS_OFF + (size_t)b * OUTPTS_B + t] = fmaxf(acc * A + B, 0.f);
        }
        if (t < 3) out[b * OUTXYZ_B + t] = xyz[b * XYZ_B_STRIDE + t];
    } else {
        // ============== group tile: KNN + gather + MLP + maxpool ==========
        int tile = bb - 2 * NB;
        int b = tile & 7;                  // consumption tracks production
        int sbase = (tile >> 3) * 4;

        // ---- stage xyz (+ norms) — overlaps the producer wait ----
        #pragma unroll 1
        for (int t = 0; t < 16; ++t) {
            int j = tid + t * 256;
            const float* p = xyz + b * XYZ_B_STRIDE + 3 + j * 3;
            float x = p[0], y = p[1], z = p[2];
            u.g.sx[j] = x; u.g.sy[j] = y; u.g.sz[j] = z;
            u.g.sn[j] = __fadd_rn(__fadd_rn(__fmul_rn(x, x), __fmul_rn(y, y)),
                                  __fmul_rn(z, z));
        }
        // ---- wait for producer: rows < sbase+4 published ----
        if (tid == 0) {
            while (__hip_atomic_load(prog + b * 16, __ATOMIC_ACQUIRE,
                                     __HIP_MEMORY_SCOPE_AGENT) < sbase + 4)
                __builtin_amdgcn_s_sleep(8);
        }
        __syncthreads();

        // ---- phase 1: KNN (wave per row) ----
        {
            int wid = tid >> 6, lane = tid & 63;
            int r = b * NPOINT + sbase + wid;
            float4 q = nxyz[r];

            float sv[16]; int si[16];
            #pragma unroll
            for (int k = 0; k < 16; ++k) { sv[k] = 3.0e38f; si[k] = 0x7fffffff; }

            #pragma unroll 1
            for (int t = 0; t < 64; ++t) {
                int j = (t << 6) + lane;
                float dot = __fadd_rn(__fadd_rn(__fmul_rn(q.x, u.g.sx[j]),
                                                __fmul_rn(q.y, u.g.sy[j])),
                                      __fmul_rn(q.z, u.g.sz[j]));
                float d2 = __fsub_rn(__fadd_rn(q.w, u.g.sn[j]), __fmul_rn(2.0f, dot));
                if (d2 < sv[15]) {        // strict <: equal keeps earlier index
                    sv[15] = d2; si[15] = j;
                    #pragma unroll
                    for (int k = 15; k > 0; --k) {
                        if (sv[k] < sv[k - 1]) {
                            float tv = sv[k]; sv[k] = sv[k - 1]; sv[k - 1] = tv;
                            int   ti = si[k]; si[k] = si[k - 1]; si[k - 1] = ti;
                        }
                    }
                }
            }
            int mykn = 0;
            #pragma unroll 1
            for (int it = 0; it < 16; ++it) {
                float bvv = sv[0]; int bii = si[0];
                #pragma unroll
                for (int off = 32; off; off >>= 1) {
                    float ov = __shfl_xor(bvv, off);
                    int   oi = __shfl_xor(bii, off);
                    if (ov < bvv || (ov == bvv && oi < bii)) { bvv = ov; bii = oi; }
                }
                if (lane == it) mykn = bii;
                bool win = (sv[0] == bvv) && (si[0] == bii);
                if (win) {
                    #pragma unroll
                    for (int k = 0; k < 15; ++k) { sv[k] = sv[k + 1]; si[k] = si[k + 1]; }
                    sv[15] = 3.0e38f; si[15] = 0x7fffffff;
                }
            }
            if (lane < 16) u.g.kk[wid][lane] = mykn;
        }
        __syncthreads();

        // ---- phase 2: MLP, quarter-split ----
        int h4 = tid & 3, ch = tid >> 2;      // ch in [0,64)
        int ch2 = ch + 64;
        float4 w0a[4], w0b[4], w1a[8], w1b[8];
        {
            const float4* pA = (const float4*)(sw0 + ch  * 64 + h4 * 16);
            const float4* pB = (const float4*)(sw0 + ch2 * 64 + h4 * 16);
            #pragma unroll
            for (int i = 0; i < 4; ++i) { w0a[i] = pA[i]; w0b[i] = pB[i]; }
            const float4* qA = (const float4*)(sw1 + ch  * 128 + h4 * 32);
            const float4* qB = (const float4*)(sw1 + ch2 * 128 + h4 * 32);
            #pragma unroll
            for (int i = 0; i < 8; ++i) { w1a[i] = qA[i]; w1b[i] = qB[i]; }
        }
        float A0a = sg0[ch]  / sqrtf(sv0[ch]  + 1e-5f);
        float B0a = (sb0[ch]  - sm0[ch])  * A0a + sbt0[ch];
        float A0b = sg0[ch2] / sqrtf(sv0[ch2] + 1e-5f);
        float B0b = (sb0[ch2] - sm0[ch2]) * A0b + sbt0[ch2];
        float A1a = sg1[ch]  / sqrtf(sv1[ch]  + 1e-5f);
        float B1a = (sb1[ch]  - sm1[ch])  * A1a + sbt1[ch];
        float A1b = sg1[ch2] / sqrtf(sv1[ch2] + 1e-5f);
        float B1b = (sb1[ch2] - sm1[ch2]) * A1b + sbt1[ch2];
        int hpA = (ch  >> 5) * 36 + (ch  & 31);
        int hpB = (ch2 >> 5) * 36 + (ch2 & 31);

        for (int row = 0; row < 4; ++row) {
            int s = sbase + row;
            float4 nq = nxyz[b * NPOINT + s];
            #pragma unroll
            for (int i = 0; i < 4; ++i) {
                int e = tid + (i << 8);
                int k = e >> 6, c = e & 63;
                int j = u.g.kk[row][k];
                float v;
                if (c < 3) {
                    float g = (c == 0) ? u.g.sx[j] : ((c == 1) ? u.g.sy[j] : u.g.sz[j]);
                    float n = (c == 0) ? nq.x : ((c == 1) ? nq.y : nq.z);
                    v = __fsub_rn(g, n);
                } else {
                    v = pts[(size_t)b * PTS_B_STRIDE + 61 + (size_t)j * 61 + (c - 3)];
                }
                u.g.feat[e] = v;
            }
            __syncthreads();
            #pragma unroll 1
            for (int k = 0; k < 16; ++k) {
                const float4* fv = (const float4*)(u.g.feat + (k << 6) + (h4 << 4));
                float a0 = 0.f, a1 = 0.f;
                #pragma unroll
                for (int i = 0; i < 4; ++i) {
                    float4 f = fv[i];
                    a0 = fmaf(w0a[i].x, f.x, a0); a1 = fmaf(w0b[i].x, f.x, a1);
                    a0 = fmaf(w0a[i].y, f.y, a0); a1 = fmaf(w0b[i].y, f.y, a1);
                    a0 = fmaf(w0a[i].z, f.z, a0); a1 = fmaf(w0b[i].z, f.z, a1);
                    a0 = fmaf(w0a[i].w, f.w, a0); a1 = fmaf(w0b[i].w, f.w, a1);
                }
                a0 = dpp_addq<0x4E>(dpp_addq<0xB1>(a0));
                a1 = dpp_addq<0x4E>(dpp_addq<0xB1>(a1));
                if (h4 == 0) {
                    u.g.hbuf[k * 144 + hpA] = fmaxf(a0 * A0a + B0a, 0.f);
                    u.g.hbuf[k * 144 + hpB] = fmaxf(a1 * A0b + B0b, 0.f);
                }
            }
            __syncthreads();
            float mx0 = 0.f, mx1 = 0.f;
            #pragma unroll 1
            for (int k = 0; k < 16; ++k) {
                const float4* hv = (const float4*)(u.g.hbuf + k * 144 + h4 * 36);
                float a0 = 0.f, a1 = 0.f;
                #pragma unroll
                for (int i = 0; i < 8; ++i) {
                    float4 f = hv[i];
                    a0 = fmaf(w1a[i].x, f.x, a0); a1 = fmaf(w1b[i].x, f.x, a1);
                    a0 = fmaf(w1a[i].y, f.y, a0); a1 = fmaf(w1b[i].y, f.y, a1);
                    a0 = fmaf(w1a[i].z, f.z, a0); a1 = fmaf(w1b[i].z, f.z, a1);
                    a0 = fmaf(w1a[i].w, f.w, a0); a1 = fmaf(w1b[i].w, f.w, a1);
                }
                a0 = dpp_addq<0x4E>(dpp_addq<0xB1>(a0));
                a1 = dpp_addq<0x4E>(dpp_addq<0xB1>(a1));
                mx0 = fmaxf(mx0, fmaxf(a0 * A1a + B1a, 0.f));
                mx1 = fmaxf(mx1, fmaxf(a1 * A1b + B1b, 0.f));
            }
            if (h4 == 0) {
                size_t ob = OUT_PTS_OFF + (size_t)b * OUTPTS_B + (size_t)(1 + s) * 128;
                out[ob + ch]  = mx0;
                out[ob + ch2] = mx1;
            }
            __syncthreads();
        }
    }
}

// ---------------------------------------------------------------------------
extern "C" void kernel_launch(void* const* d_in, const int* in_sizes, int n_in,
                              void* d_out, int out_size, void* d_ws, size_t ws_size,
                              hipStream_t stream) {
    const float* xyz = (const float*)d_in[0];
    const float* pts = (const float*)d_in[1];
    // dict order: sa0 block, cls0 block, sa1 block, cls1 block
    const float* sa_w0 = (const float*)d_in[2];
    const float* sa_b0 = (const float*)d_in[3];
    const float* sa_g0 = (const float*)d_in[4];
    const float* sa_bt0 = (const float*)d_in[5];
    const float* sa_m0 = (const float*)d_in[6];
    const float* sa_v0 = (const float*)d_in[7];
    const float* cls_w0 = (const float*)d_in[8];
    const float* cls_b0 = (const float*)d_in[9];
    const float* cls_g0 = (const float*)d_in[10];
    const float* cls_bt0 = (const float*)d_in[11];
    const float* cls_m0 = (const float*)d_in[12];
    const float* cls_v0 = (const float*)d_in[13];
    const float* sa_w1 = (const float*)d_in[14];
    const float* sa_b1 = (const float*)d_in[15];
    const float* sa_g1 = (const float*)d_in[16];
    const float* sa_bt1 = (const float*)d_in[17];
    const float* sa_m1 = (const float*)d_in[18];
    const float* sa_v1 = (const float*)d_in[19];
    const float* cls_w1 = (const float*)d_in[20];
    const float* cls_b1 = (const float*)d_in[21];
    const float* cls_g1 = (const float*)d_in[22];
    const float* cls_bt1 = (const float*)d_in[23];
    const float* cls_m1 = (const float*)d_in[24];
    const float* cls_v1 = (const float*)d_in[25];

    float* out = (float*)d_out;
    float4* nxyz_ws = (float4*)d_ws;                          // 8192 * 16 B
    int* prog = (int*)((char*)d_ws + NB * NPOINT * sizeof(float4));  // 8 slots, 64B apart

    int grid = 2 * NB + NB * (NPOINT / 4);    // 8 fps + 8 cls + 2048 tiles
    fused_kernel<<<grid, 256, 0, stream>>>(xyz, pts,
        sa_w0, sa_b0, sa_g0, sa_bt0, sa_m0, sa_v0,
        sa_w1, sa_b1, sa_g1, sa_bt1, sa_m1, sa_v1,
        cls_w0, cls_b0, cls_g0, cls_bt0, cls_m0, cls_v0,
        cls_w1, cls_b1, cls_g1, cls_bt1, cls_m1, cls_v1,
        nxyz_ws, prog, out);
}